// Round 8
// baseline (483.243 us; speedup 1.0000x reference)
//
#include <hip/hip_runtime.h>
#include <math.h>

#define NU 100000
#define NB 50000
#define NI 100000
#define D 64
#define NLAYER 3
#define NNZ 2000000
#define BATCH 8192
#define LEAKY 0.2f
#define N_UB (NU + NB)   // 150000
#define N_IU (NI + NU)   // 200000

#define VSCALE 16383.f   // 14-bit fixed-point for vals in [0,1)

// ---- windowed CSR build params ----
#define WBITS 11
#define WSZ 2048                        // node window (small -> many blocks)
#define NWC ((N_IU + WSZ - 1) / WSZ)    // 98
#define NWR ((N_UB + WSZ - 1) / WSZ)    // 74
#define NWIN (NWC + NWR)                // 172
#define CAPC 21504                      // mean 20480 + 7.2 sigma
#define CAPR 28672                      // mean 27307 + 8.3 sigma
#define EPB 8192                        // edges per bucket block
#define NBLK_B ((NNZ + EPB - 1) / EPB)  // 245
#define CONCAT_BLKS 512
#define GBLK 384                        // 384*64 = 24576 = 3*BATCH exactly

typedef unsigned long long u64;
typedef float v2f __attribute__((ext_vector_type(2)));

// ---- fp8 e4m3 x4 pack/unpack (hardware cvt; roundtrip-consistent) ----
__device__ __forceinline__ unsigned pack_fp8x4(float a, float b, float c,
                                               float d) {
  int lo = __builtin_amdgcn_cvt_pk_fp8_f32(a, b, 0, false);
  int pk = __builtin_amdgcn_cvt_pk_fp8_f32(c, d, lo, true);
  return (unsigned)pk;
}
__device__ __forceinline__ void unpack_fp8x4(unsigned w, float f[4]) {
  v2f lo = __builtin_amdgcn_cvt_pk_f32_fp8((int)w, false);
  v2f hi = __builtin_amdgcn_cvt_pk_f32_fp8((int)w, true);
  f[0] = lo[0];
  f[1] = lo[1];
  f[2] = hi[0];
  f[3] = hi[1];
}

// ---------------------------------------------------------------------------
// bucket pass: partition edges into 2048-node windows for both sides.
// record: payload32 = q<<18 | partner ; rec = payload<<11 | node_local
// NT stores: buffers are read exactly once by the sort.
// ---------------------------------------------------------------------------
__global__ __launch_bounds__(1024) void bucket_kernel(
    const int* __restrict__ rows, const int* __restrict__ cols,
    const float* __restrict__ vals, int* __restrict__ gcurC,
    int* __restrict__ gcurR, u64* __restrict__ bufC, u64* __restrict__ bufR) {
  __shared__ int cntw[NWIN];
  __shared__ int basew[NWIN];
  int t = threadIdx.x;
  if (t < NWIN) cntw[t] = 0;
  __syncthreads();
  int e0 = blockIdx.x * EPB;
  int e1 = e0 + EPB;
  if (e1 > NNZ) e1 = NNZ;
  for (int e = e0 + t; e < e1; e += 1024) {
    int c = cols[e];
    int r = rows[e];
    atomicAdd(&cntw[c >> WBITS], 1);
    atomicAdd(&cntw[NWC + (r >> WBITS)], 1);
  }
  __syncthreads();
  if (t < NWC)
    basew[t] = atomicAdd(&gcurC[t], cntw[t]);
  else if (t < NWIN)
    basew[t] = atomicAdd(&gcurR[t - NWC], cntw[t]);
  __syncthreads();
  if (t < NWIN) cntw[t] = 0;  // reuse as local cursors
  __syncthreads();
  for (int e = e0 + t; e < e1; e += 1024) {
    int c = cols[e];
    int r = rows[e];
    unsigned q = __float2uint_rn(vals[e] * VSCALE);
    int wc = c >> WBITS;
    int wr = r >> WBITS;
    int oc = atomicAdd(&cntw[wc], 1);
    u64 recC = ((u64)((q << 18) | (unsigned)r) << WBITS) |
               (unsigned)(c & (WSZ - 1));
    __builtin_nontemporal_store(recC, &bufC[(size_t)wc * CAPC + basew[wc] + oc]);
    int orr = atomicAdd(&cntw[NWC + wr], 1);
    u64 recR = ((u64)((q << 18) | (unsigned)c) << WBITS) |
               (unsigned)(r & (WSZ - 1));
    __builtin_nontemporal_store(recR,
                                &bufR[(size_t)wr * CAPR + basew[NWC + wr] + orr]);
  }
}

// ---------------------------------------------------------------------------
// fused dispatch:
//   blocks [0, NWIN): per-window LDS counting sort -> ptr slice + ec/er
//   blocks [NWIN, NWIN+CONCAT_BLKS): concat emb -> x (fp8) + l2 reduction
//   blocks [NWIN+CONCAT_BLKS, +GBLK): x0 gather -> uacc/bacc (direct write)
// ---------------------------------------------------------------------------
__global__ __launch_bounds__(1024) void csr_concat_kernel(
    const u64* __restrict__ bufC, const u64* __restrict__ bufR,
    const int* __restrict__ gcurC, const int* __restrict__ gcurR,
    unsigned* __restrict__ ec, unsigned* __restrict__ er,
    int* __restrict__ ptrc, int* __restrict__ ptrr,
    const float* __restrict__ emb_u, const float* __restrict__ emb_b,
    unsigned* __restrict__ x, float* __restrict__ out,
    const int* __restrict__ u_idx, const int* __restrict__ b_idx,
    float* __restrict__ uacc, float* __restrict__ bacc) {
  __shared__ int lcnt[WSZ];
  __shared__ int wsum[16];
  __shared__ float fsum[16];
  __shared__ int wbase_s;
  int blk = blockIdx.x;
  int t = threadIdx.x;

  if (blk >= NWIN + CONCAT_BLKS) {
    // ---------------- x0 gather path (write, no +=) ----------------
    int i = (blk - NWIN - CONCAT_BLKS) * 64 + (t >> 4);
    int g = t & 15;
    const float* srcrow;
    float* dst;
    if (i < BATCH) {
      srcrow = emb_u + (size_t)u_idx[i] * D;
      dst = uacc + (size_t)i * D;
    } else {
      int j = i - BATCH;
      srcrow = emb_b + (size_t)b_idx[j] * D;
      dst = bacc + (size_t)j * D;
    }
    *(float4*)&dst[4 * g] = *(const float4*)&srcrow[4 * g];
    return;
  }

  if (blk >= NWIN) {
    // ---------------- concat + l2 path (fp8 out) ----------------
    const int total4 = (N_UB * D) / 4;
    const int nu4 = (NU * D) / 4;
    float sq = 0.f;
    for (int i = (blk - NWIN) * 1024 + t; i < total4; i += CONCAT_BLKS * 1024) {
      float4 v = (i < nu4) ? ((const float4*)emb_u)[i]
                           : ((const float4*)emb_b)[i - nu4];
      sq += v.x * v.x + v.y * v.y + v.z * v.z + v.w * v.w;
      x[i] = pack_fp8x4(v.x, v.y, v.z, v.w);
    }
    for (int off = 32; off; off >>= 1) sq += __shfl_down(sq, off);
    if ((t & 63) == 0) fsum[t >> 6] = sq;
    __syncthreads();
    if (t == 0) {
      float s = 0.f;
      for (int k = 0; k < 16; ++k) s += fsum[k];
      atomicAdd(&out[1], s * (0.5f / (float)NU));
    }
    return;
  }

  // ---------------- windowed counting-sort path ----------------
  bool cside = blk < NWC;
  int win = cside ? blk : blk - NWC;
  const u64* buf = cside ? bufC + (size_t)win * CAPC : bufR + (size_t)win * CAPR;
  const int* gsz = cside ? gcurC : gcurR;
  int nwin = cside ? NWC : NWR;
  int nnode = cside ? N_IU : N_UB;
  unsigned* eo = cside ? ec : er;
  int* ptr = cside ? ptrc : ptrr;
  int cnt = gsz[win];
  // winbase = sum of gsz[0..win) via LDS atomics (once per block)
  if (t == 0) wbase_s = 0;
  __syncthreads();
  if (t < win) atomicAdd(&wbase_s, gsz[t]);

  lcnt[t] = 0;
  lcnt[t + 1024] = 0;
  __syncthreads();
  int winbase = wbase_s;
  // pass 1: histogram over window-local node ids
  for (int i = t; i < cnt; i += 1024)
    atomicAdd(&lcnt[(int)(__builtin_nontemporal_load(&buf[i]) & (WSZ - 1))], 1);
  __syncthreads();
  // exclusive scan of 2048 counters: 2 serial/thread + wave-shfl block scan
  int i0 = 2 * t;
  int a = lcnt[i0], b = lcnt[i0 + 1];
  int s = a + b;
  int lane = t & 63, wid = t >> 6;
  int v = s;
#pragma unroll
  for (int off = 1; off < 64; off <<= 1) {
    int n = __shfl_up(v, off);
    if (lane >= off) v += n;
  }
  if (lane == 63) wsum[wid] = v;
  __syncthreads();
  if (t == 0) {
    int run = 0;
    for (int k = 0; k < 16; ++k) {
      int tmp = wsum[k];
      wsum[k] = run;
      run += tmp;
    }
  }
  __syncthreads();
  int excl = v - s + wsum[wid];
  lcnt[i0] = excl;
  lcnt[i0 + 1] = excl + a;
  __syncthreads();
  // write global ptr slice
  int gnode0 = win * WSZ;
  for (int j = t; j < WSZ; j += 1024) {
    int g = gnode0 + j;
    if (g < nnode) ptr[g] = winbase + lcnt[j];
  }
  if (t == 0 && win == nwin - 1) ptr[nnode] = NNZ;
  __syncthreads();
  // pass 2: scatter payloads (window's output region is L2-resident)
  for (int i = t; i < cnt; i += 1024) {
    u64 rec = __builtin_nontemporal_load(&buf[i]);
    int pos = winbase + atomicAdd(&lcnt[(int)(rec & (WSZ - 1))], 1);
    eo[pos] = (unsigned)(rec >> WBITS);
  }
}

// ---------------------------------------------------------------------------
// pass 1 (CSR by col): y[c] = leaky(filt[c]) * sum val*x[src]
// fp8 rows: 16 lanes/row, u32 (4 dims) per lane, 4 rows per wave; unroll 4.
// ---------------------------------------------------------------------------
__global__ __launch_bounds__(256) void spmm_col_kernel(
    const int* __restrict__ ptrc, const unsigned* __restrict__ ec,
    const unsigned* __restrict__ x, const float* __restrict__ filt,
    unsigned* __restrict__ y) {
  int wv = blockIdx.x * 4 + (threadIdx.x >> 6);
  int lane = threadIdx.x & 63;
  int g = lane & 15;
  int c = wv * 4 + (lane >> 4);
  if (c >= N_IU) return;
  int e = ptrc[c], e2 = ptrc[c + 1];
  float a0 = 0.f, a1 = 0.f, a2 = 0.f, a3 = 0.f;
  for (; e + 4 <= e2; e += 4) {
    unsigned p0 = __builtin_nontemporal_load(&ec[e]);
    unsigned p1 = __builtin_nontemporal_load(&ec[e + 1]);
    unsigned p2 = __builtin_nontemporal_load(&ec[e + 2]);
    unsigned p3 = __builtin_nontemporal_load(&ec[e + 3]);
    unsigned w0 = x[(size_t)(p0 & 0x3FFFFu) * 16 + g];
    unsigned w1 = x[(size_t)(p1 & 0x3FFFFu) * 16 + g];
    unsigned w2 = x[(size_t)(p2 & 0x3FFFFu) * 16 + g];
    unsigned w3 = x[(size_t)(p3 & 0x3FFFFu) * 16 + g];
    float f0[4], f1[4], f2[4], f3[4];
    unpack_fp8x4(w0, f0);
    unpack_fp8x4(w1, f1);
    unpack_fp8x4(w2, f2);
    unpack_fp8x4(w3, f3);
    float v0 = (float)(p0 >> 18), v1 = (float)(p1 >> 18);
    float v2 = (float)(p2 >> 18), v3 = (float)(p3 >> 18);
    a0 += v0 * f0[0] + v1 * f1[0] + v2 * f2[0] + v3 * f3[0];
    a1 += v0 * f0[1] + v1 * f1[1] + v2 * f2[1] + v3 * f3[1];
    a2 += v0 * f0[2] + v1 * f1[2] + v2 * f2[2] + v3 * f3[2];
    a3 += v0 * f0[3] + v1 * f1[3] + v2 * f2[3] + v3 * f3[3];
  }
  for (; e < e2; ++e) {
    unsigned p = __builtin_nontemporal_load(&ec[e]);
    unsigned w = x[(size_t)(p & 0x3FFFFu) * 16 + g];
    float f4[4];
    unpack_fp8x4(w, f4);
    float v = (float)(p >> 18);
    a0 += v * f4[0];
    a1 += v * f4[1];
    a2 += v * f4[2];
    a3 += v * f4[3];
  }
  float fw = filt[c];
  float f = (fw > 0.f ? fw : LEAKY * fw) * (1.f / VSCALE);
  y[(size_t)c * 16 + g] = pack_fp8x4(a0 * f, a1 * f, a2 * f, a3 * f);
}

// ---------------------------------------------------------------------------
// pass 2 (CSR by row): x[r] = sum val*y[src]
// ---------------------------------------------------------------------------
__global__ __launch_bounds__(256) void spmm_row_kernel(
    const int* __restrict__ ptrr, const unsigned* __restrict__ er,
    const unsigned* __restrict__ y, unsigned* __restrict__ x) {
  int wv = blockIdx.x * 4 + (threadIdx.x >> 6);
  int lane = threadIdx.x & 63;
  int g = lane & 15;
  int r = wv * 4 + (lane >> 4);
  if (r >= N_UB) return;
  int e = ptrr[r], e2 = ptrr[r + 1];
  float a0 = 0.f, a1 = 0.f, a2 = 0.f, a3 = 0.f;
  for (; e + 4 <= e2; e += 4) {
    unsigned p0 = __builtin_nontemporal_load(&er[e]);
    unsigned p1 = __builtin_nontemporal_load(&er[e + 1]);
    unsigned p2 = __builtin_nontemporal_load(&er[e + 2]);
    unsigned p3 = __builtin_nontemporal_load(&er[e + 3]);
    unsigned w0 = y[(size_t)(p0 & 0x3FFFFu) * 16 + g];
    unsigned w1 = y[(size_t)(p1 & 0x3FFFFu) * 16 + g];
    unsigned w2 = y[(size_t)(p2 & 0x3FFFFu) * 16 + g];
    unsigned w3 = y[(size_t)(p3 & 0x3FFFFu) * 16 + g];
    float f0[4], f1[4], f2[4], f3[4];
    unpack_fp8x4(w0, f0);
    unpack_fp8x4(w1, f1);
    unpack_fp8x4(w2, f2);
    unpack_fp8x4(w3, f3);
    float v0 = (float)(p0 >> 18), v1 = (float)(p1 >> 18);
    float v2 = (float)(p2 >> 18), v3 = (float)(p3 >> 18);
    a0 += v0 * f0[0] + v1 * f1[0] + v2 * f2[0] + v3 * f3[0];
    a1 += v0 * f0[1] + v1 * f1[1] + v2 * f2[1] + v3 * f3[1];
    a2 += v0 * f0[2] + v1 * f1[2] + v2 * f2[2] + v3 * f3[2];
    a3 += v0 * f0[3] + v1 * f1[3] + v2 * f2[3] + v3 * f3[3];
  }
  for (; e < e2; ++e) {
    unsigned p = __builtin_nontemporal_load(&er[e]);
    unsigned w = y[(size_t)(p & 0x3FFFFu) * 16 + g];
    float f4[4];
    unpack_fp8x4(w, f4);
    float v = (float)(p >> 18);
    a0 += v * f4[0];
    a1 += v * f4[1];
    a2 += v * f4[2];
    a3 += v * f4[3];
  }
  const float s = 1.f / VSCALE;
  x[(size_t)r * 16 + g] = pack_fp8x4(a0 * s, a1 * s, a2 * s, a3 * s);
}

// ---------------------------------------------------------------------------
// last layer pass 2 ONLY at gathered rows, accumulated into uacc/bacc (fp32)
// ---------------------------------------------------------------------------
__global__ __launch_bounds__(256) void spmm_gather_last_kernel(
    const int* __restrict__ ptrr, const unsigned* __restrict__ er,
    const unsigned* __restrict__ y, const int* __restrict__ u_idx,
    const int* __restrict__ b_idx, float* __restrict__ uacc,
    float* __restrict__ bacc) {
  int wv = blockIdx.x * 4 + (threadIdx.x >> 6);
  int lane = threadIdx.x & 63;
  int g = lane & 15;
  int i = wv * 4 + (lane >> 4);
  if (i >= 3 * BATCH) return;
  int row;
  float* dst;
  if (i < BATCH) {
    row = u_idx[i];
    dst = &uacc[(size_t)i * D];
  } else {
    int j = i - BATCH;
    row = NU + b_idx[j];
    dst = &bacc[(size_t)j * D];
  }
  int e = ptrr[row], e2 = ptrr[row + 1];
  float a0 = 0.f, a1 = 0.f, a2 = 0.f, a3 = 0.f;
  for (; e < e2; ++e) {
    unsigned p = er[e];
    unsigned w = y[(size_t)(p & 0x3FFFFu) * 16 + g];
    float f4[4];
    unpack_fp8x4(w, f4);
    float v = (float)(p >> 18);
    a0 += v * f4[0];
    a1 += v * f4[1];
    a2 += v * f4[2];
    a3 += v * f4[3];
  }
  const float s = 1.f / VSCALE;
  float4* dp = (float4*)&dst[4 * g];
  float4 d = *dp;
  d.x += a0 * s;
  d.y += a1 * s;
  d.z += a2 * s;
  d.w += a3 * s;
  *dp = d;
}

// ---------------------------------------------------------------------------
// gather-accumulate (intermediate layers): fp8 x -> fp32 acc
// ---------------------------------------------------------------------------
__global__ __launch_bounds__(256) void gather_acc_kernel(
    const unsigned* __restrict__ x, const int* __restrict__ u_idx,
    const int* __restrict__ b_idx, float* __restrict__ uacc,
    float* __restrict__ bacc) {
  int wv = blockIdx.x * 4 + (threadIdx.x >> 6);
  int lane = threadIdx.x & 63;
  int g = lane & 15;
  int i = wv * 4 + (lane >> 4);
  if (i >= 3 * BATCH) return;
  int src;
  float* dst;
  if (i < BATCH) {
    src = u_idx[i];
    dst = &uacc[(size_t)i * D];
  } else {
    int j = i - BATCH;
    src = NU + b_idx[j];
    dst = &bacc[(size_t)j * D];
  }
  float f4[4];
  unpack_fp8x4(x[(size_t)src * 16 + g], f4);
  float4* dp = (float4*)&dst[4 * g];
  float4 d = *dp;
  d.x += f4[0];
  d.y += f4[1];
  d.z += f4[2];
  d.w += f4[3];
  *dp = d;
}

// ---------------------------------------------------------------------------
// loss: z = dot(u, b1-b0)/16; loss = mean softplus(z).
// grid-stride; register-accumulated; ONE atomic per block (256 total).
// ---------------------------------------------------------------------------
__global__ __launch_bounds__(256) void loss_kernel(
    const float* __restrict__ uacc, const float* __restrict__ bacc,
    float* __restrict__ out) {
  __shared__ float bsum[8];
  int t = threadIdx.x;
  int slot = t >> 5;  // 8 half-waves per block
  int sub = t & 31;
  float acc = 0.f;
  for (int i = blockIdx.x * 8 + slot; i < BATCH; i += gridDim.x * 8) {
    float2 u = *(const float2*)&uacc[(size_t)i * D + 2 * sub];
    float2 b0 = *(const float2*)&bacc[(size_t)(2 * i) * D + 2 * sub];
    float2 b1 = *(const float2*)&bacc[(size_t)(2 * i + 1) * D + 2 * sub];
    float tt = (u.x * (b1.x - b0.x) + u.y * (b1.y - b0.y)) * (1.f / 16.f);
    for (int off = 16; off; off >>= 1) tt += __shfl_down(tt, off, 32);
    if (sub == 0) {
      float z = tt;
      acc += z > 0.f ? z + log1pf(expf(-z)) : log1pf(expf(z));
    }
  }
  if (sub == 0) bsum[slot] = acc;
  __syncthreads();
  if (t == 0) {
    float s = 0.f;
    for (int k = 0; k < 8; ++k) s += bsum[k];
    atomicAdd(&out[0], s * (1.f / (float)BATCH));
  }
}

extern "C" void kernel_launch(void* const* d_in, const int* in_sizes, int n_in,
                              void* d_out, int out_size, void* d_ws,
                              size_t ws_size, hipStream_t stream) {
  const float* emb_u = (const float*)d_in[0];
  const float* emb_b = (const float*)d_in[1];
  const float* filter_w = (const float*)d_in[2];
  const float* vals = (const float*)d_in[3];
  const int* rows = (const int*)d_in[4];
  const int* cols = (const int*)d_in[5];
  const int* u_idx = (const int*)d_in[6];
  const int* b_idx = (const int*)d_in[7];
  float* out = (float*)d_out;

  // workspace layout: bucket buffers (dead after CSR build) ALIASED with yH
  // only; uacc/bacc un-aliased (written during csr_concat's gather blocks).
  char* base = (char*)d_ws;
  u64* bufC = (u64*)base;                               // NWC*CAPC u64
  u64* bufR = bufC + (size_t)NWC * CAPC;                // NWR*CAPR u64
  unsigned* yH = (unsigned*)base;                       // N_IU*16 u32 (alias)
  char* after = base + ((size_t)NWC * CAPC + (size_t)NWR * CAPR) * 8;
  unsigned* xA = (unsigned*)after;                      // N_UB*16 u32
  unsigned* ec = xA + (size_t)N_UB * 16;                // NNZ
  unsigned* er = ec + NNZ;                              // NNZ
  int* ptrc = (int*)(er + NNZ);                         // N_IU+1
  int* ptrr = ptrc + (N_IU + 1);                        // N_UB+1
  int* gcurC = ptrr + (N_UB + 1);                       // NWC
  int* gcurR = gcurC + NWC;                             // NWR
  float* uacc = (float*)(gcurR + NWR);                  // BATCH*D
  float* bacc = uacc + (size_t)BATCH * D;               // 2*BATCH*D

  hipMemsetAsync(out, 0, 2 * sizeof(float), stream);
  hipMemsetAsync(gcurC, 0, NWIN * sizeof(int), stream);

  // bucket edges by node-window (both sides)
  bucket_kernel<<<NBLK_B, 1024, 0, stream>>>(rows, cols, vals, gcurC, gcurR,
                                             bufC, bufR);
  // fused: per-window counting sort + concat->fp8 + l2 + x0 gather
  csr_concat_kernel<<<NWIN + CONCAT_BLKS + GBLK, 1024, 0, stream>>>(
      bufC, bufR, gcurC, gcurR, ec, er, ptrc, ptrr, emb_u, emb_b, xA, out,
      u_idx, b_idx, uacc, bacc);

  // ---- 3 layers ----
  for (int l = 0; l < NLAYER; ++l) {
    spmm_col_kernel<<<(N_IU + 15) / 16, 256, 0, stream>>>(
        ptrc, ec, xA, filter_w + (size_t)l * N_IU, yH);
    if (l < NLAYER - 1) {
      spmm_row_kernel<<<(N_UB + 15) / 16, 256, 0, stream>>>(ptrr, er, yH, xA);
      gather_acc_kernel<<<(3 * BATCH + 15) / 16, 256, 0, stream>>>(
          xA, u_idx, b_idx, uacc, bacc);
    } else {
      spmm_gather_last_kernel<<<(3 * BATCH + 15) / 16, 256, 0, stream>>>(
          ptrr, er, yH, u_idx, b_idx, uacc, bacc);
    }
  }

  loss_kernel<<<256, 256, 0, stream>>>(uacc, bacc, out);
}

// Round 9
// 362.016 us; speedup vs baseline: 1.3349x; 1.3349x over previous
//
#include <hip/hip_runtime.h>
#include <math.h>

#define NU 100000
#define NB 50000
#define NI 100000
#define D 64
#define NLAYER 3
#define NNZ 2000000
#define BATCH 8192
#define LEAKY 0.2f
#define N_UB (NU + NB)   // 150000
#define N_IU (NI + NU)   // 200000

#define VSCALE 16383.f   // 14-bit fixed-point for vals in [0,1)

// ---- windowed CSR build params ----
#define WBITS 11
#define WSZ 2048                        // node window (small -> many blocks)
#define NWC ((N_IU + WSZ - 1) / WSZ)    // 98
#define NWR ((N_UB + WSZ - 1) / WSZ)    // 74
#define NWIN (NWC + NWR)                // 172
#define CAPC 21504                      // mean 20480 + 7.2 sigma
#define CAPR 28672                      // mean 27307 + 8.3 sigma
#define EPB 8192                        // edges per bucket block
#define NBLK_B ((NNZ + EPB - 1) / EPB)  // 245
#define CONCAT_BLKS 512
#define GBLK 384                        // 384*64 = 24576 = 3*BATCH exactly

typedef unsigned long long u64;
typedef float v2f __attribute__((ext_vector_type(2)));

// ---- fp8 e4m3 x4 pack/unpack (hardware cvt; roundtrip-consistent) ----
__device__ __forceinline__ unsigned pack_fp8x4(float a, float b, float c,
                                               float d) {
  int lo = __builtin_amdgcn_cvt_pk_fp8_f32(a, b, 0, false);
  int pk = __builtin_amdgcn_cvt_pk_fp8_f32(c, d, lo, true);
  return (unsigned)pk;
}
__device__ __forceinline__ void unpack_fp8x4(unsigned w, float f[4]) {
  v2f lo = __builtin_amdgcn_cvt_pk_f32_fp8((int)w, false);
  v2f hi = __builtin_amdgcn_cvt_pk_f32_fp8((int)w, true);
  f[0] = lo[0];
  f[1] = lo[1];
  f[2] = hi[0];
  f[3] = hi[1];
}

// ---------------------------------------------------------------------------
// bucket pass: partition edges into 2048-node windows for both sides.
// record: payload32 = q<<18 | partner ; rec = payload<<11 | node_local
// PLAIN stores (L2-coalesced; NT here cost 5x write amplification in R8).
// ---------------------------------------------------------------------------
__global__ __launch_bounds__(1024) void bucket_kernel(
    const int* __restrict__ rows, const int* __restrict__ cols,
    const float* __restrict__ vals, int* __restrict__ gcurC,
    int* __restrict__ gcurR, u64* __restrict__ bufC, u64* __restrict__ bufR) {
  __shared__ int cntw[NWIN];
  __shared__ int basew[NWIN];
  int t = threadIdx.x;
  if (t < NWIN) cntw[t] = 0;
  __syncthreads();
  int e0 = blockIdx.x * EPB;
  int e1 = e0 + EPB;
  if (e1 > NNZ) e1 = NNZ;
  for (int e = e0 + t; e < e1; e += 1024) {
    int c = cols[e];
    int r = rows[e];
    atomicAdd(&cntw[c >> WBITS], 1);
    atomicAdd(&cntw[NWC + (r >> WBITS)], 1);
  }
  __syncthreads();
  if (t < NWC)
    basew[t] = atomicAdd(&gcurC[t], cntw[t]);
  else if (t < NWIN)
    basew[t] = atomicAdd(&gcurR[t - NWC], cntw[t]);
  __syncthreads();
  if (t < NWIN) cntw[t] = 0;  // reuse as local cursors
  __syncthreads();
  for (int e = e0 + t; e < e1; e += 1024) {
    int c = cols[e];
    int r = rows[e];
    unsigned q = __float2uint_rn(vals[e] * VSCALE);
    int wc = c >> WBITS;
    int wr = r >> WBITS;
    int oc = atomicAdd(&cntw[wc], 1);
    u64 recC = ((u64)((q << 18) | (unsigned)r) << WBITS) |
               (unsigned)(c & (WSZ - 1));
    bufC[(size_t)wc * CAPC + basew[wc] + oc] = recC;
    int orr = atomicAdd(&cntw[NWC + wr], 1);
    u64 recR = ((u64)((q << 18) | (unsigned)c) << WBITS) |
               (unsigned)(r & (WSZ - 1));
    bufR[(size_t)wr * CAPR + basew[NWC + wr] + orr] = recR;
  }
}

// ---------------------------------------------------------------------------
// fused dispatch:
//   blocks [0, NWIN): per-window LDS counting sort -> ptr slice + ec/er
//   blocks [NWIN, NWIN+CONCAT_BLKS): concat emb -> x (fp8) + l2 reduction
//   blocks [NWIN+CONCAT_BLKS, +GBLK): x0 gather -> uacc/bacc (direct write)
// PLAIN loads on buf (read twice: histogram + scatter -> wants L2).
// ---------------------------------------------------------------------------
__global__ __launch_bounds__(1024) void csr_concat_kernel(
    const u64* __restrict__ bufC, const u64* __restrict__ bufR,
    const int* __restrict__ gcurC, const int* __restrict__ gcurR,
    unsigned* __restrict__ ec, unsigned* __restrict__ er,
    int* __restrict__ ptrc, int* __restrict__ ptrr,
    const float* __restrict__ emb_u, const float* __restrict__ emb_b,
    unsigned* __restrict__ x, float* __restrict__ out,
    const int* __restrict__ u_idx, const int* __restrict__ b_idx,
    float* __restrict__ uacc, float* __restrict__ bacc) {
  __shared__ int lcnt[WSZ];
  __shared__ int wsum[16];
  __shared__ float fsum[16];
  __shared__ int wbase_s;
  int blk = blockIdx.x;
  int t = threadIdx.x;

  if (blk >= NWIN + CONCAT_BLKS) {
    // ---------------- x0 gather path (write, no +=) ----------------
    int i = (blk - NWIN - CONCAT_BLKS) * 64 + (t >> 4);
    int g = t & 15;
    const float* srcrow;
    float* dst;
    if (i < BATCH) {
      srcrow = emb_u + (size_t)u_idx[i] * D;
      dst = uacc + (size_t)i * D;
    } else {
      int j = i - BATCH;
      srcrow = emb_b + (size_t)b_idx[j] * D;
      dst = bacc + (size_t)j * D;
    }
    *(float4*)&dst[4 * g] = *(const float4*)&srcrow[4 * g];
    return;
  }

  if (blk >= NWIN) {
    // ---------------- concat + l2 path (fp8 out) ----------------
    const int total4 = (N_UB * D) / 4;
    const int nu4 = (NU * D) / 4;
    float sq = 0.f;
    for (int i = (blk - NWIN) * 1024 + t; i < total4; i += CONCAT_BLKS * 1024) {
      float4 v = (i < nu4) ? ((const float4*)emb_u)[i]
                           : ((const float4*)emb_b)[i - nu4];
      sq += v.x * v.x + v.y * v.y + v.z * v.z + v.w * v.w;
      x[i] = pack_fp8x4(v.x, v.y, v.z, v.w);
    }
    for (int off = 32; off; off >>= 1) sq += __shfl_down(sq, off);
    if ((t & 63) == 0) fsum[t >> 6] = sq;
    __syncthreads();
    if (t == 0) {
      float s = 0.f;
      for (int k = 0; k < 16; ++k) s += fsum[k];
      atomicAdd(&out[1], s * (0.5f / (float)NU));
    }
    return;
  }

  // ---------------- windowed counting-sort path ----------------
  bool cside = blk < NWC;
  int win = cside ? blk : blk - NWC;
  const u64* buf = cside ? bufC + (size_t)win * CAPC : bufR + (size_t)win * CAPR;
  const int* gsz = cside ? gcurC : gcurR;
  int nwin = cside ? NWC : NWR;
  int nnode = cside ? N_IU : N_UB;
  unsigned* eo = cside ? ec : er;
  int* ptr = cside ? ptrc : ptrr;
  int cnt = gsz[win];
  // winbase = sum of gsz[0..win) via LDS atomics (once per block)
  if (t == 0) wbase_s = 0;
  __syncthreads();
  if (t < win) atomicAdd(&wbase_s, gsz[t]);

  lcnt[t] = 0;
  lcnt[t + 1024] = 0;
  __syncthreads();
  int winbase = wbase_s;
  // pass 1: histogram over window-local node ids
  for (int i = t; i < cnt; i += 1024)
    atomicAdd(&lcnt[(int)(buf[i] & (WSZ - 1))], 1);
  __syncthreads();
  // exclusive scan of 2048 counters: 2 serial/thread + wave-shfl block scan
  int i0 = 2 * t;
  int a = lcnt[i0], b = lcnt[i0 + 1];
  int s = a + b;
  int lane = t & 63, wid = t >> 6;
  int v = s;
#pragma unroll
  for (int off = 1; off < 64; off <<= 1) {
    int n = __shfl_up(v, off);
    if (lane >= off) v += n;
  }
  if (lane == 63) wsum[wid] = v;
  __syncthreads();
  if (t == 0) {
    int run = 0;
    for (int k = 0; k < 16; ++k) {
      int tmp = wsum[k];
      wsum[k] = run;
      run += tmp;
    }
  }
  __syncthreads();
  int excl = v - s + wsum[wid];
  lcnt[i0] = excl;
  lcnt[i0 + 1] = excl + a;
  __syncthreads();
  // write global ptr slice
  int gnode0 = win * WSZ;
  for (int j = t; j < WSZ; j += 1024) {
    int g = gnode0 + j;
    if (g < nnode) ptr[g] = winbase + lcnt[j];
  }
  if (t == 0 && win == nwin - 1) ptr[nnode] = NNZ;
  __syncthreads();
  // pass 2: scatter payloads (window's output region is L2-resident)
  for (int i = t; i < cnt; i += 1024) {
    u64 rec = buf[i];
    int pos = winbase + atomicAdd(&lcnt[(int)(rec & (WSZ - 1))], 1);
    eo[pos] = (unsigned)(rec >> WBITS);
  }
}

// ---------------------------------------------------------------------------
// pass 1 (CSR by col): y[c] = leaky(filt[c]) * sum val*x[src]
// fp8 rows: 16 lanes/row, u32 (4 dims) per lane, 4 rows per wave; unroll 4.
// NT loads kept on edge stream only (truly read-once).
// ---------------------------------------------------------------------------
__global__ __launch_bounds__(256) void spmm_col_kernel(
    const int* __restrict__ ptrc, const unsigned* __restrict__ ec,
    const unsigned* __restrict__ x, const float* __restrict__ filt,
    unsigned* __restrict__ y) {
  int wv = blockIdx.x * 4 + (threadIdx.x >> 6);
  int lane = threadIdx.x & 63;
  int g = lane & 15;
  int c = wv * 4 + (lane >> 4);
  if (c >= N_IU) return;
  int e = ptrc[c], e2 = ptrc[c + 1];
  float a0 = 0.f, a1 = 0.f, a2 = 0.f, a3 = 0.f;
  for (; e + 4 <= e2; e += 4) {
    unsigned p0 = __builtin_nontemporal_load(&ec[e]);
    unsigned p1 = __builtin_nontemporal_load(&ec[e + 1]);
    unsigned p2 = __builtin_nontemporal_load(&ec[e + 2]);
    unsigned p3 = __builtin_nontemporal_load(&ec[e + 3]);
    unsigned w0 = x[(size_t)(p0 & 0x3FFFFu) * 16 + g];
    unsigned w1 = x[(size_t)(p1 & 0x3FFFFu) * 16 + g];
    unsigned w2 = x[(size_t)(p2 & 0x3FFFFu) * 16 + g];
    unsigned w3 = x[(size_t)(p3 & 0x3FFFFu) * 16 + g];
    float f0[4], f1[4], f2[4], f3[4];
    unpack_fp8x4(w0, f0);
    unpack_fp8x4(w1, f1);
    unpack_fp8x4(w2, f2);
    unpack_fp8x4(w3, f3);
    float v0 = (float)(p0 >> 18), v1 = (float)(p1 >> 18);
    float v2 = (float)(p2 >> 18), v3 = (float)(p3 >> 18);
    a0 += v0 * f0[0] + v1 * f1[0] + v2 * f2[0] + v3 * f3[0];
    a1 += v0 * f0[1] + v1 * f1[1] + v2 * f2[1] + v3 * f3[1];
    a2 += v0 * f0[2] + v1 * f1[2] + v2 * f2[2] + v3 * f3[2];
    a3 += v0 * f0[3] + v1 * f1[3] + v2 * f2[3] + v3 * f3[3];
  }
  for (; e < e2; ++e) {
    unsigned p = __builtin_nontemporal_load(&ec[e]);
    unsigned w = x[(size_t)(p & 0x3FFFFu) * 16 + g];
    float f4[4];
    unpack_fp8x4(w, f4);
    float v = (float)(p >> 18);
    a0 += v * f4[0];
    a1 += v * f4[1];
    a2 += v * f4[2];
    a3 += v * f4[3];
  }
  float fw = filt[c];
  float f = (fw > 0.f ? fw : LEAKY * fw) * (1.f / VSCALE);
  y[(size_t)c * 16 + g] = pack_fp8x4(a0 * f, a1 * f, a2 * f, a3 * f);
}

// ---------------------------------------------------------------------------
// pass 2 (CSR by row): x[r] = sum val*y[src]
// ---------------------------------------------------------------------------
__global__ __launch_bounds__(256) void spmm_row_kernel(
    const int* __restrict__ ptrr, const unsigned* __restrict__ er,
    const unsigned* __restrict__ y, unsigned* __restrict__ x) {
  int wv = blockIdx.x * 4 + (threadIdx.x >> 6);
  int lane = threadIdx.x & 63;
  int g = lane & 15;
  int r = wv * 4 + (lane >> 4);
  if (r >= N_UB) return;
  int e = ptrr[r], e2 = ptrr[r + 1];
  float a0 = 0.f, a1 = 0.f, a2 = 0.f, a3 = 0.f;
  for (; e + 4 <= e2; e += 4) {
    unsigned p0 = __builtin_nontemporal_load(&er[e]);
    unsigned p1 = __builtin_nontemporal_load(&er[e + 1]);
    unsigned p2 = __builtin_nontemporal_load(&er[e + 2]);
    unsigned p3 = __builtin_nontemporal_load(&er[e + 3]);
    unsigned w0 = y[(size_t)(p0 & 0x3FFFFu) * 16 + g];
    unsigned w1 = y[(size_t)(p1 & 0x3FFFFu) * 16 + g];
    unsigned w2 = y[(size_t)(p2 & 0x3FFFFu) * 16 + g];
    unsigned w3 = y[(size_t)(p3 & 0x3FFFFu) * 16 + g];
    float f0[4], f1[4], f2[4], f3[4];
    unpack_fp8x4(w0, f0);
    unpack_fp8x4(w1, f1);
    unpack_fp8x4(w2, f2);
    unpack_fp8x4(w3, f3);
    float v0 = (float)(p0 >> 18), v1 = (float)(p1 >> 18);
    float v2 = (float)(p2 >> 18), v3 = (float)(p3 >> 18);
    a0 += v0 * f0[0] + v1 * f1[0] + v2 * f2[0] + v3 * f3[0];
    a1 += v0 * f0[1] + v1 * f1[1] + v2 * f2[1] + v3 * f3[1];
    a2 += v0 * f0[2] + v1 * f1[2] + v2 * f2[2] + v3 * f3[2];
    a3 += v0 * f0[3] + v1 * f1[3] + v2 * f2[3] + v3 * f3[3];
  }
  for (; e < e2; ++e) {
    unsigned p = __builtin_nontemporal_load(&er[e]);
    unsigned w = y[(size_t)(p & 0x3FFFFu) * 16 + g];
    float f4[4];
    unpack_fp8x4(w, f4);
    float v = (float)(p >> 18);
    a0 += v * f4[0];
    a1 += v * f4[1];
    a2 += v * f4[2];
    a3 += v * f4[3];
  }
  const float s = 1.f / VSCALE;
  x[(size_t)r * 16 + g] = pack_fp8x4(a0 * s, a1 * s, a2 * s, a3 * s);
}

// ---------------------------------------------------------------------------
// last layer pass 2 ONLY at gathered rows, accumulated into uacc/bacc (fp32)
// ---------------------------------------------------------------------------
__global__ __launch_bounds__(256) void spmm_gather_last_kernel(
    const int* __restrict__ ptrr, const unsigned* __restrict__ er,
    const unsigned* __restrict__ y, const int* __restrict__ u_idx,
    const int* __restrict__ b_idx, float* __restrict__ uacc,
    float* __restrict__ bacc) {
  int wv = blockIdx.x * 4 + (threadIdx.x >> 6);
  int lane = threadIdx.x & 63;
  int g = lane & 15;
  int i = wv * 4 + (lane >> 4);
  if (i >= 3 * BATCH) return;
  int row;
  float* dst;
  if (i < BATCH) {
    row = u_idx[i];
    dst = &uacc[(size_t)i * D];
  } else {
    int j = i - BATCH;
    row = NU + b_idx[j];
    dst = &bacc[(size_t)j * D];
  }
  int e = ptrr[row], e2 = ptrr[row + 1];
  float a0 = 0.f, a1 = 0.f, a2 = 0.f, a3 = 0.f;
  for (; e < e2; ++e) {
    unsigned p = er[e];
    unsigned w = y[(size_t)(p & 0x3FFFFu) * 16 + g];
    float f4[4];
    unpack_fp8x4(w, f4);
    float v = (float)(p >> 18);
    a0 += v * f4[0];
    a1 += v * f4[1];
    a2 += v * f4[2];
    a3 += v * f4[3];
  }
  const float s = 1.f / VSCALE;
  float4* dp = (float4*)&dst[4 * g];
  float4 d = *dp;
  d.x += a0 * s;
  d.y += a1 * s;
  d.z += a2 * s;
  d.w += a3 * s;
  *dp = d;
}

// ---------------------------------------------------------------------------
// gather-accumulate (intermediate layers): fp8 x -> fp32 acc
// ---------------------------------------------------------------------------
__global__ __launch_bounds__(256) void gather_acc_kernel(
    const unsigned* __restrict__ x, const int* __restrict__ u_idx,
    const int* __restrict__ b_idx, float* __restrict__ uacc,
    float* __restrict__ bacc) {
  int wv = blockIdx.x * 4 + (threadIdx.x >> 6);
  int lane = threadIdx.x & 63;
  int g = lane & 15;
  int i = wv * 4 + (lane >> 4);
  if (i >= 3 * BATCH) return;
  int src;
  float* dst;
  if (i < BATCH) {
    src = u_idx[i];
    dst = &uacc[(size_t)i * D];
  } else {
    int j = i - BATCH;
    src = NU + b_idx[j];
    dst = &bacc[(size_t)j * D];
  }
  float f4[4];
  unpack_fp8x4(x[(size_t)src * 16 + g], f4);
  float4* dp = (float4*)&dst[4 * g];
  float4 d = *dp;
  d.x += f4[0];
  d.y += f4[1];
  d.z += f4[2];
  d.w += f4[3];
  *dp = d;
}

// ---------------------------------------------------------------------------
// loss: z = dot(u, b1-b0)/16; loss = mean softplus(z).
// grid-stride; register-accumulated; ONE atomic per block (256 total).
// ---------------------------------------------------------------------------
__global__ __launch_bounds__(256) void loss_kernel(
    const float* __restrict__ uacc, const float* __restrict__ bacc,
    float* __restrict__ out) {
  __shared__ float bsum[8];
  int t = threadIdx.x;
  int slot = t >> 5;  // 8 half-waves per block
  int sub = t & 31;
  float acc = 0.f;
  for (int i = blockIdx.x * 8 + slot; i < BATCH; i += gridDim.x * 8) {
    float2 u = *(const float2*)&uacc[(size_t)i * D + 2 * sub];
    float2 b0 = *(const float2*)&bacc[(size_t)(2 * i) * D + 2 * sub];
    float2 b1 = *(const float2*)&bacc[(size_t)(2 * i + 1) * D + 2 * sub];
    float tt = (u.x * (b1.x - b0.x) + u.y * (b1.y - b0.y)) * (1.f / 16.f);
    for (int off = 16; off; off >>= 1) tt += __shfl_down(tt, off, 32);
    if (sub == 0) {
      float z = tt;
      acc += z > 0.f ? z + log1pf(expf(-z)) : log1pf(expf(z));
    }
  }
  if (sub == 0) bsum[slot] = acc;
  __syncthreads();
  if (t == 0) {
    float s = 0.f;
    for (int k = 0; k < 8; ++k) s += bsum[k];
    atomicAdd(&out[0], s * (1.f / (float)BATCH));
  }
}

extern "C" void kernel_launch(void* const* d_in, const int* in_sizes, int n_in,
                              void* d_out, int out_size, void* d_ws,
                              size_t ws_size, hipStream_t stream) {
  const float* emb_u = (const float*)d_in[0];
  const float* emb_b = (const float*)d_in[1];
  const float* filter_w = (const float*)d_in[2];
  const float* vals = (const float*)d_in[3];
  const int* rows = (const int*)d_in[4];
  const int* cols = (const int*)d_in[5];
  const int* u_idx = (const int*)d_in[6];
  const int* b_idx = (const int*)d_in[7];
  float* out = (float*)d_out;

  // workspace layout: bucket buffers (dead after CSR build) ALIASED with yH
  // only; uacc/bacc un-aliased (written during csr_concat's gather blocks).
  char* base = (char*)d_ws;
  u64* bufC = (u64*)base;                               // NWC*CAPC u64
  u64* bufR = bufC + (size_t)NWC * CAPC;                // NWR*CAPR u64
  unsigned* yH = (unsigned*)base;                       // N_IU*16 u32 (alias)
  char* after = base + ((size_t)NWC * CAPC + (size_t)NWR * CAPR) * 8;
  unsigned* xA = (unsigned*)after;                      // N_UB*16 u32
  unsigned* ec = xA + (size_t)N_UB * 16;                // NNZ
  unsigned* er = ec + NNZ;                              // NNZ
  int* ptrc = (int*)(er + NNZ);                         // N_IU+1
  int* ptrr = ptrc + (N_IU + 1);                        // N_UB+1
  int* gcurC = ptrr + (N_UB + 1);                       // NWC
  int* gcurR = gcurC + NWC;                             // NWR
  float* uacc = (float*)(gcurR + NWR);                  // BATCH*D
  float* bacc = uacc + (size_t)BATCH * D;               // 2*BATCH*D

  hipMemsetAsync(out, 0, 2 * sizeof(float), stream);
  hipMemsetAsync(gcurC, 0, NWIN * sizeof(int), stream);

  // bucket edges by node-window (both sides)
  bucket_kernel<<<NBLK_B, 1024, 0, stream>>>(rows, cols, vals, gcurC, gcurR,
                                             bufC, bufR);
  // fused: per-window counting sort + concat->fp8 + l2 + x0 gather
  csr_concat_kernel<<<NWIN + CONCAT_BLKS + GBLK, 1024, 0, stream>>>(
      bufC, bufR, gcurC, gcurR, ec, er, ptrc, ptrr, emb_u, emb_b, xA, out,
      u_idx, b_idx, uacc, bacc);

  // ---- 3 layers ----
  for (int l = 0; l < NLAYER; ++l) {
    spmm_col_kernel<<<(N_IU + 15) / 16, 256, 0, stream>>>(
        ptrc, ec, xA, filter_w + (size_t)l * N_IU, yH);
    if (l < NLAYER - 1) {
      spmm_row_kernel<<<(N_UB + 15) / 16, 256, 0, stream>>>(ptrr, er, yH, xA);
      gather_acc_kernel<<<(3 * BATCH + 15) / 16, 256, 0, stream>>>(
          xA, u_idx, b_idx, uacc, bacc);
    } else {
      spmm_gather_last_kernel<<<(3 * BATCH + 15) / 16, 256, 0, stream>>>(
          ptrr, er, yH, u_idx, b_idx, uacc, bacc);
    }
  }

  loss_kernel<<<256, 256, 0, stream>>>(uacc, bacc, out);
}

// Round 10
// 352.828 us; speedup vs baseline: 1.3696x; 1.0260x over previous
//
#include <hip/hip_runtime.h>
#include <math.h>

#define NU 100000
#define NB 50000
#define NI 100000
#define D 64
#define NLAYER 3
#define NNZ 2000000
#define BATCH 8192
#define LEAKY 0.2f
#define N_UB (NU + NB)   // 150000
#define N_IU (NI + NU)   // 200000

#define VSCALE 16383.f   // 14-bit fixed-point for vals in [0,1)

// ---- windowed CSR build params ----
#define WBITS 11
#define WSZ 2048                        // node window (small -> many blocks)
#define NWC ((N_IU + WSZ - 1) / WSZ)    // 98
#define NWR ((N_UB + WSZ - 1) / WSZ)    // 74
#define NWIN (NWC + NWR)                // 172
#define CAPC 21504                      // mean 20480 + 7.2 sigma
#define CAPR 28672                      // mean 27307 + 8.3 sigma
#define EPB 8192                        // edges per bucket block
#define NBLK_B ((NNZ + EPB - 1) / EPB)  // 245
#define CONCAT_BLKS 512
#define GBLK 384                        // 384*64 = 24576 = 3*BATCH (1024-thr)
#define NCOLB ((N_IU + 15) / 16)        // 12500 col blocks (256-thr)
#define NROWB ((N_UB + 15) / 16)        // 9375 row blocks
#define GAB ((3 * BATCH) / 16)          // 1536 gather blocks (256-thr)

typedef unsigned long long u64;
typedef float v2f __attribute__((ext_vector_type(2)));

// ---- fp8 e4m3 x4 pack/unpack (hardware cvt; roundtrip-consistent) ----
__device__ __forceinline__ unsigned pack_fp8x4(float a, float b, float c,
                                               float d) {
  int lo = __builtin_amdgcn_cvt_pk_fp8_f32(a, b, 0, false);
  int pk = __builtin_amdgcn_cvt_pk_fp8_f32(c, d, lo, true);
  return (unsigned)pk;
}
__device__ __forceinline__ void unpack_fp8x4(unsigned w, float f[4]) {
  v2f lo = __builtin_amdgcn_cvt_pk_f32_fp8((int)w, false);
  v2f hi = __builtin_amdgcn_cvt_pk_f32_fp8((int)w, true);
  f[0] = lo[0];
  f[1] = lo[1];
  f[2] = hi[0];
  f[3] = hi[1];
}

// ---------------------------------------------------------------------------
// bucket pass: partition edges into 2048-node windows for both sides.
// record: payload32 = q<<18 | partner ; rec = payload<<11 | node_local
// PER-WAVE histograms + cursors (16 copies) -> 16x less LDS atomic collision.
// ---------------------------------------------------------------------------
__global__ __launch_bounds__(1024) void bucket_kernel(
    const int* __restrict__ rows, const int* __restrict__ cols,
    const float* __restrict__ vals, int* __restrict__ gcurC,
    int* __restrict__ gcurR, u64* __restrict__ bufC, u64* __restrict__ bufR) {
  __shared__ int cntw[16][NWIN];
  __shared__ int basew[16][NWIN];
  int t = threadIdx.x;
  int wid = t >> 6;
  for (int i = t; i < 16 * NWIN; i += 1024) (&cntw[0][0])[i] = 0;
  __syncthreads();
  int e0 = blockIdx.x * EPB;
  int e1 = e0 + EPB;
  if (e1 > NNZ) e1 = NNZ;
  // pass 1: per-wave counts
  for (int e = e0 + t; e < e1; e += 1024) {
    int c = cols[e];
    int r = rows[e];
    atomicAdd(&cntw[wid][c >> WBITS], 1);
    atomicAdd(&cntw[wid][NWC + (r >> WBITS)], 1);
  }
  __syncthreads();
  // reserve global ranges; compute per-wave absolute bases
  for (int w = t; w < NWIN; w += 1024) {
    int tot = 0;
#pragma unroll
    for (int k = 0; k < 16; ++k) tot += cntw[k][w];
    int base = (w < NWC) ? atomicAdd(&gcurC[w], tot)
                         : atomicAdd(&gcurR[w - NWC], tot);
#pragma unroll
    for (int k = 0; k < 16; ++k) {
      basew[k][w] = base;
      base += cntw[k][w];
    }
  }
  __syncthreads();
  for (int i = t; i < 16 * NWIN; i += 1024) (&cntw[0][0])[i] = 0;
  __syncthreads();
  // pass 2: write records via per-wave cursors
  for (int e = e0 + t; e < e1; e += 1024) {
    int c = cols[e];
    int r = rows[e];
    unsigned q = __float2uint_rn(vals[e] * VSCALE);
    int wc = c >> WBITS;
    int wr = r >> WBITS;
    int oc = atomicAdd(&cntw[wid][wc], 1);
    u64 recC = ((u64)((q << 18) | (unsigned)r) << WBITS) |
               (unsigned)(c & (WSZ - 1));
    bufC[(size_t)wc * CAPC + basew[wid][wc] + oc] = recC;
    int orr = atomicAdd(&cntw[wid][NWC + wr], 1);
    u64 recR = ((u64)((q << 18) | (unsigned)c) << WBITS) |
               (unsigned)(r & (WSZ - 1));
    bufR[(size_t)wr * CAPR + basew[wid][NWC + wr] + orr] = recR;
  }
}

// ---------------------------------------------------------------------------
// fused dispatch:
//   blocks [0, NWIN): per-window LDS counting sort -> ptr slice + ec/er
//   blocks [NWIN, NWIN+CONCAT_BLKS): concat emb -> x (fp8) + l2 reduction
//   blocks [NWIN+CONCAT_BLKS, +GBLK): x0 gather -> uacc/bacc (direct write)
// ---------------------------------------------------------------------------
__global__ __launch_bounds__(1024) void csr_concat_kernel(
    const u64* __restrict__ bufC, const u64* __restrict__ bufR,
    const int* __restrict__ gcurC, const int* __restrict__ gcurR,
    unsigned* __restrict__ ec, unsigned* __restrict__ er,
    int* __restrict__ ptrc, int* __restrict__ ptrr,
    const float* __restrict__ emb_u, const float* __restrict__ emb_b,
    unsigned* __restrict__ x, float* __restrict__ out,
    const int* __restrict__ u_idx, const int* __restrict__ b_idx,
    float* __restrict__ uacc, float* __restrict__ bacc) {
  __shared__ int lcnt[WSZ];
  __shared__ int wsum[16];
  __shared__ float fsum[16];
  __shared__ int wbase_s;
  int blk = blockIdx.x;
  int t = threadIdx.x;

  if (blk >= NWIN + CONCAT_BLKS) {
    // ---------------- x0 gather path (write, no +=) ----------------
    int i = (blk - NWIN - CONCAT_BLKS) * 64 + (t >> 4);
    int g = t & 15;
    const float* srcrow;
    float* dst;
    if (i < BATCH) {
      srcrow = emb_u + (size_t)u_idx[i] * D;
      dst = uacc + (size_t)i * D;
    } else {
      int j = i - BATCH;
      srcrow = emb_b + (size_t)b_idx[j] * D;
      dst = bacc + (size_t)j * D;
    }
    *(float4*)&dst[4 * g] = *(const float4*)&srcrow[4 * g];
    return;
  }

  if (blk >= NWIN) {
    // ---------------- concat + l2 path (fp8 out) ----------------
    const int total4 = (N_UB * D) / 4;
    const int nu4 = (NU * D) / 4;
    float sq = 0.f;
    for (int i = (blk - NWIN) * 1024 + t; i < total4; i += CONCAT_BLKS * 1024) {
      float4 v = (i < nu4) ? ((const float4*)emb_u)[i]
                           : ((const float4*)emb_b)[i - nu4];
      sq += v.x * v.x + v.y * v.y + v.z * v.z + v.w * v.w;
      x[i] = pack_fp8x4(v.x, v.y, v.z, v.w);
    }
    for (int off = 32; off; off >>= 1) sq += __shfl_down(sq, off);
    if ((t & 63) == 0) fsum[t >> 6] = sq;
    __syncthreads();
    if (t == 0) {
      float s = 0.f;
      for (int k = 0; k < 16; ++k) s += fsum[k];
      atomicAdd(&out[1], s * (0.5f / (float)NU));
    }
    return;
  }

  // ---------------- windowed counting-sort path ----------------
  bool cside = blk < NWC;
  int win = cside ? blk : blk - NWC;
  const u64* buf = cside ? bufC + (size_t)win * CAPC : bufR + (size_t)win * CAPR;
  const int* gsz = cside ? gcurC : gcurR;
  int nwin = cside ? NWC : NWR;
  int nnode = cside ? N_IU : N_UB;
  unsigned* eo = cside ? ec : er;
  int* ptr = cside ? ptrc : ptrr;
  int cnt = gsz[win];
  // winbase = sum of gsz[0..win) via LDS atomics (once per block)
  if (t == 0) wbase_s = 0;
  __syncthreads();
  if (t < win) atomicAdd(&wbase_s, gsz[t]);

  lcnt[t] = 0;
  lcnt[t + 1024] = 0;
  __syncthreads();
  int winbase = wbase_s;
  // pass 1: histogram over window-local node ids
  for (int i = t; i < cnt; i += 1024)
    atomicAdd(&lcnt[(int)(buf[i] & (WSZ - 1))], 1);
  __syncthreads();
  // exclusive scan of 2048 counters: 2 serial/thread + wave-shfl block scan
  int i0 = 2 * t;
  int a = lcnt[i0], b = lcnt[i0 + 1];
  int s = a + b;
  int lane = t & 63, wid = t >> 6;
  int v = s;
#pragma unroll
  for (int off = 1; off < 64; off <<= 1) {
    int n = __shfl_up(v, off);
    if (lane >= off) v += n;
  }
  if (lane == 63) wsum[wid] = v;
  __syncthreads();
  if (t == 0) {
    int run = 0;
    for (int k = 0; k < 16; ++k) {
      int tmp = wsum[k];
      wsum[k] = run;
      run += tmp;
    }
  }
  __syncthreads();
  int excl = v - s + wsum[wid];
  lcnt[i0] = excl;
  lcnt[i0 + 1] = excl + a;
  __syncthreads();
  // write global ptr slice
  int gnode0 = win * WSZ;
  for (int j = t; j < WSZ; j += 1024) {
    int g = gnode0 + j;
    if (g < nnode) ptr[g] = winbase + lcnt[j];
  }
  if (t == 0 && win == nwin - 1) ptr[nnode] = NNZ;
  __syncthreads();
  // pass 2: scatter payloads (window's output region is L2-resident)
  for (int i = t; i < cnt; i += 1024) {
    u64 rec = buf[i];
    int pos = winbase + atomicAdd(&lcnt[(int)(rec & (WSZ - 1))], 1);
    eo[pos] = (unsigned)(rec >> WBITS);
  }
}

// ---------------------------------------------------------------------------
// pass 1 (CSR by col): y[c] = leaky(filt[c]) * sum val*x[src]
// fp8 rows: 16 lanes/row, 4 rows/wave; unroll 8 batched (8 gathers in flight).
// Extra blocks [NCOLB,NCOLB+GAB): gather-acc of x into uacc/bacc (layers 1,2).
// ---------------------------------------------------------------------------
__global__ __launch_bounds__(256) void spmm_col_kernel(
    const int* __restrict__ ptrc, const unsigned* __restrict__ ec,
    const unsigned* __restrict__ x, const float* __restrict__ filt,
    unsigned* __restrict__ y, const int* __restrict__ u_idx,
    const int* __restrict__ b_idx, float* __restrict__ uacc,
    float* __restrict__ bacc) {
  int blk = blockIdx.x;
  if (blk >= NCOLB) {
    // -------- fused gather-acc path --------
    int t = threadIdx.x;
    int i = (blk - NCOLB) * 16 + (t >> 4);
    int g = t & 15;
    int src;
    float* dst;
    if (i < BATCH) {
      src = u_idx[i];
      dst = &uacc[(size_t)i * D];
    } else {
      int j = i - BATCH;
      src = NU + b_idx[j];
      dst = &bacc[(size_t)j * D];
    }
    float f4[4];
    unpack_fp8x4(x[(size_t)src * 16 + g], f4);
    float4* dp = (float4*)&dst[4 * g];
    float4 d = *dp;
    d.x += f4[0];
    d.y += f4[1];
    d.z += f4[2];
    d.w += f4[3];
    *dp = d;
    return;
  }
  int wv = blk * 4 + (threadIdx.x >> 6);
  int lane = threadIdx.x & 63;
  int g = lane & 15;
  int c = wv * 4 + (lane >> 4);
  if (c >= N_IU) return;
  int e = ptrc[c], e2 = ptrc[c + 1];
  float a0 = 0.f, a1 = 0.f, a2 = 0.f, a3 = 0.f;
  for (; e + 8 <= e2; e += 8) {
    unsigned p0 = __builtin_nontemporal_load(&ec[e]);
    unsigned p1 = __builtin_nontemporal_load(&ec[e + 1]);
    unsigned p2 = __builtin_nontemporal_load(&ec[e + 2]);
    unsigned p3 = __builtin_nontemporal_load(&ec[e + 3]);
    unsigned p4 = __builtin_nontemporal_load(&ec[e + 4]);
    unsigned p5 = __builtin_nontemporal_load(&ec[e + 5]);
    unsigned p6 = __builtin_nontemporal_load(&ec[e + 6]);
    unsigned p7 = __builtin_nontemporal_load(&ec[e + 7]);
    unsigned w0 = x[(size_t)(p0 & 0x3FFFFu) * 16 + g];
    unsigned w1 = x[(size_t)(p1 & 0x3FFFFu) * 16 + g];
    unsigned w2 = x[(size_t)(p2 & 0x3FFFFu) * 16 + g];
    unsigned w3 = x[(size_t)(p3 & 0x3FFFFu) * 16 + g];
    unsigned w4 = x[(size_t)(p4 & 0x3FFFFu) * 16 + g];
    unsigned w5 = x[(size_t)(p5 & 0x3FFFFu) * 16 + g];
    unsigned w6 = x[(size_t)(p6 & 0x3FFFFu) * 16 + g];
    unsigned w7 = x[(size_t)(p7 & 0x3FFFFu) * 16 + g];
    float f0[4], f1[4], f2[4], f3[4], f4_[4], f5[4], f6[4], f7[4];
    unpack_fp8x4(w0, f0);
    unpack_fp8x4(w1, f1);
    unpack_fp8x4(w2, f2);
    unpack_fp8x4(w3, f3);
    unpack_fp8x4(w4, f4_);
    unpack_fp8x4(w5, f5);
    unpack_fp8x4(w6, f6);
    unpack_fp8x4(w7, f7);
    float v0 = (float)(p0 >> 18), v1 = (float)(p1 >> 18);
    float v2 = (float)(p2 >> 18), v3 = (float)(p3 >> 18);
    float v4 = (float)(p4 >> 18), v5 = (float)(p5 >> 18);
    float v6 = (float)(p6 >> 18), v7 = (float)(p7 >> 18);
    a0 += v0 * f0[0] + v1 * f1[0] + v2 * f2[0] + v3 * f3[0] + v4 * f4_[0] +
          v5 * f5[0] + v6 * f6[0] + v7 * f7[0];
    a1 += v0 * f0[1] + v1 * f1[1] + v2 * f2[1] + v3 * f3[1] + v4 * f4_[1] +
          v5 * f5[1] + v6 * f6[1] + v7 * f7[1];
    a2 += v0 * f0[2] + v1 * f1[2] + v2 * f2[2] + v3 * f3[2] + v4 * f4_[2] +
          v5 * f5[2] + v6 * f6[2] + v7 * f7[2];
    a3 += v0 * f0[3] + v1 * f1[3] + v2 * f2[3] + v3 * f3[3] + v4 * f4_[3] +
          v5 * f5[3] + v6 * f6[3] + v7 * f7[3];
  }
  for (; e + 4 <= e2; e += 4) {
    unsigned p0 = __builtin_nontemporal_load(&ec[e]);
    unsigned p1 = __builtin_nontemporal_load(&ec[e + 1]);
    unsigned p2 = __builtin_nontemporal_load(&ec[e + 2]);
    unsigned p3 = __builtin_nontemporal_load(&ec[e + 3]);
    unsigned w0 = x[(size_t)(p0 & 0x3FFFFu) * 16 + g];
    unsigned w1 = x[(size_t)(p1 & 0x3FFFFu) * 16 + g];
    unsigned w2 = x[(size_t)(p2 & 0x3FFFFu) * 16 + g];
    unsigned w3 = x[(size_t)(p3 & 0x3FFFFu) * 16 + g];
    float f0[4], f1[4], f2[4], f3[4];
    unpack_fp8x4(w0, f0);
    unpack_fp8x4(w1, f1);
    unpack_fp8x4(w2, f2);
    unpack_fp8x4(w3, f3);
    float v0 = (float)(p0 >> 18), v1 = (float)(p1 >> 18);
    float v2 = (float)(p2 >> 18), v3 = (float)(p3 >> 18);
    a0 += v0 * f0[0] + v1 * f1[0] + v2 * f2[0] + v3 * f3[0];
    a1 += v0 * f0[1] + v1 * f1[1] + v2 * f2[1] + v3 * f3[1];
    a2 += v0 * f0[2] + v1 * f1[2] + v2 * f2[2] + v3 * f3[2];
    a3 += v0 * f0[3] + v1 * f1[3] + v2 * f2[3] + v3 * f3[3];
  }
  for (; e < e2; ++e) {
    unsigned p = __builtin_nontemporal_load(&ec[e]);
    unsigned w = x[(size_t)(p & 0x3FFFFu) * 16 + g];
    float f4[4];
    unpack_fp8x4(w, f4);
    float v = (float)(p >> 18);
    a0 += v * f4[0];
    a1 += v * f4[1];
    a2 += v * f4[2];
    a3 += v * f4[3];
  }
  float fw = filt[c];
  float f = (fw > 0.f ? fw : LEAKY * fw) * (1.f / VSCALE);
  y[(size_t)c * 16 + g] = pack_fp8x4(a0 * f, a1 * f, a2 * f, a3 * f);
}

// ---------------------------------------------------------------------------
// pass 2 (CSR by row): x[r] = sum val*y[src]; unroll 8 batched.
// ---------------------------------------------------------------------------
__global__ __launch_bounds__(256) void spmm_row_kernel(
    const int* __restrict__ ptrr, const unsigned* __restrict__ er,
    const unsigned* __restrict__ y, unsigned* __restrict__ x) {
  int wv = blockIdx.x * 4 + (threadIdx.x >> 6);
  int lane = threadIdx.x & 63;
  int g = lane & 15;
  int r = wv * 4 + (lane >> 4);
  if (r >= N_UB) return;
  int e = ptrr[r], e2 = ptrr[r + 1];
  float a0 = 0.f, a1 = 0.f, a2 = 0.f, a3 = 0.f;
  for (; e + 8 <= e2; e += 8) {
    unsigned p0 = __builtin_nontemporal_load(&er[e]);
    unsigned p1 = __builtin_nontemporal_load(&er[e + 1]);
    unsigned p2 = __builtin_nontemporal_load(&er[e + 2]);
    unsigned p3 = __builtin_nontemporal_load(&er[e + 3]);
    unsigned p4 = __builtin_nontemporal_load(&er[e + 4]);
    unsigned p5 = __builtin_nontemporal_load(&er[e + 5]);
    unsigned p6 = __builtin_nontemporal_load(&er[e + 6]);
    unsigned p7 = __builtin_nontemporal_load(&er[e + 7]);
    unsigned w0 = y[(size_t)(p0 & 0x3FFFFu) * 16 + g];
    unsigned w1 = y[(size_t)(p1 & 0x3FFFFu) * 16 + g];
    unsigned w2 = y[(size_t)(p2 & 0x3FFFFu) * 16 + g];
    unsigned w3 = y[(size_t)(p3 & 0x3FFFFu) * 16 + g];
    unsigned w4 = y[(size_t)(p4 & 0x3FFFFu) * 16 + g];
    unsigned w5 = y[(size_t)(p5 & 0x3FFFFu) * 16 + g];
    unsigned w6 = y[(size_t)(p6 & 0x3FFFFu) * 16 + g];
    unsigned w7 = y[(size_t)(p7 & 0x3FFFFu) * 16 + g];
    float f0[4], f1[4], f2[4], f3[4], f4_[4], f5[4], f6[4], f7[4];
    unpack_fp8x4(w0, f0);
    unpack_fp8x4(w1, f1);
    unpack_fp8x4(w2, f2);
    unpack_fp8x4(w3, f3);
    unpack_fp8x4(w4, f4_);
    unpack_fp8x4(w5, f5);
    unpack_fp8x4(w6, f6);
    unpack_fp8x4(w7, f7);
    float v0 = (float)(p0 >> 18), v1 = (float)(p1 >> 18);
    float v2 = (float)(p2 >> 18), v3 = (float)(p3 >> 18);
    float v4 = (float)(p4 >> 18), v5 = (float)(p5 >> 18);
    float v6 = (float)(p6 >> 18), v7 = (float)(p7 >> 18);
    a0 += v0 * f0[0] + v1 * f1[0] + v2 * f2[0] + v3 * f3[0] + v4 * f4_[0] +
          v5 * f5[0] + v6 * f6[0] + v7 * f7[0];
    a1 += v0 * f0[1] + v1 * f1[1] + v2 * f2[1] + v3 * f3[1] + v4 * f4_[1] +
          v5 * f5[1] + v6 * f6[1] + v7 * f7[1];
    a2 += v0 * f0[2] + v1 * f1[2] + v2 * f2[2] + v3 * f3[2] + v4 * f4_[2] +
          v5 * f5[2] + v6 * f6[2] + v7 * f7[2];
    a3 += v0 * f0[3] + v1 * f1[3] + v2 * f2[3] + v3 * f3[3] + v4 * f4_[3] +
          v5 * f5[3] + v6 * f6[3] + v7 * f7[3];
  }
  for (; e + 4 <= e2; e += 4) {
    unsigned p0 = __builtin_nontemporal_load(&er[e]);
    unsigned p1 = __builtin_nontemporal_load(&er[e + 1]);
    unsigned p2 = __builtin_nontemporal_load(&er[e + 2]);
    unsigned p3 = __builtin_nontemporal_load(&er[e + 3]);
    unsigned w0 = y[(size_t)(p0 & 0x3FFFFu) * 16 + g];
    unsigned w1 = y[(size_t)(p1 & 0x3FFFFu) * 16 + g];
    unsigned w2 = y[(size_t)(p2 & 0x3FFFFu) * 16 + g];
    unsigned w3 = y[(size_t)(p3 & 0x3FFFFu) * 16 + g];
    float f0[4], f1[4], f2[4], f3[4];
    unpack_fp8x4(w0, f0);
    unpack_fp8x4(w1, f1);
    unpack_fp8x4(w2, f2);
    unpack_fp8x4(w3, f3);
    float v0 = (float)(p0 >> 18), v1 = (float)(p1 >> 18);
    float v2 = (float)(p2 >> 18), v3 = (float)(p3 >> 18);
    a0 += v0 * f0[0] + v1 * f1[0] + v2 * f2[0] + v3 * f3[0];
    a1 += v0 * f0[1] + v1 * f1[1] + v2 * f2[1] + v3 * f3[1];
    a2 += v0 * f0[2] + v1 * f1[2] + v2 * f2[2] + v3 * f3[2];
    a3 += v0 * f0[3] + v1 * f1[3] + v2 * f2[3] + v3 * f3[3];
  }
  for (; e < e2; ++e) {
    unsigned p = __builtin_nontemporal_load(&er[e]);
    unsigned w = y[(size_t)(p & 0x3FFFFu) * 16 + g];
    float f4[4];
    unpack_fp8x4(w, f4);
    float v = (float)(p >> 18);
    a0 += v * f4[0];
    a1 += v * f4[1];
    a2 += v * f4[2];
    a3 += v * f4[3];
  }
  const float s = 1.f / VSCALE;
  x[(size_t)r * 16 + g] = pack_fp8x4(a0 * s, a1 * s, a2 * s, a3 * s);
}

// ---------------------------------------------------------------------------
// last layer pass 2 ONLY at gathered rows, accumulated into uacc/bacc (fp32)
// ---------------------------------------------------------------------------
__global__ __launch_bounds__(256) void spmm_gather_last_kernel(
    const int* __restrict__ ptrr, const unsigned* __restrict__ er,
    const unsigned* __restrict__ y, const int* __restrict__ u_idx,
    const int* __restrict__ b_idx, float* __restrict__ uacc,
    float* __restrict__ bacc) {
  int wv = blockIdx.x * 4 + (threadIdx.x >> 6);
  int lane = threadIdx.x & 63;
  int g = lane & 15;
  int i = wv * 4 + (lane >> 4);
  if (i >= 3 * BATCH) return;
  int row;
  float* dst;
  if (i < BATCH) {
    row = u_idx[i];
    dst = &uacc[(size_t)i * D];
  } else {
    int j = i - BATCH;
    row = NU + b_idx[j];
    dst = &bacc[(size_t)j * D];
  }
  int e = ptrr[row], e2 = ptrr[row + 1];
  float a0 = 0.f, a1 = 0.f, a2 = 0.f, a3 = 0.f;
  for (; e < e2; ++e) {
    unsigned p = er[e];
    unsigned w = y[(size_t)(p & 0x3FFFFu) * 16 + g];
    float f4[4];
    unpack_fp8x4(w, f4);
    float v = (float)(p >> 18);
    a0 += v * f4[0];
    a1 += v * f4[1];
    a2 += v * f4[2];
    a3 += v * f4[3];
  }
  const float s = 1.f / VSCALE;
  float4* dp = (float4*)&dst[4 * g];
  float4 d = *dp;
  d.x += a0 * s;
  d.y += a1 * s;
  d.z += a2 * s;
  d.w += a3 * s;
  *dp = d;
}

// ---------------------------------------------------------------------------
// loss: z = dot(u, b1-b0)/16; loss = mean softplus(z).
// grid-stride; register-accumulated; ONE atomic per block (256 total).
// ---------------------------------------------------------------------------
__global__ __launch_bounds__(256) void loss_kernel(
    const float* __restrict__ uacc, const float* __restrict__ bacc,
    float* __restrict__ out) {
  __shared__ float bsum[8];
  int t = threadIdx.x;
  int slot = t >> 5;  // 8 half-waves per block
  int sub = t & 31;
  float acc = 0.f;
  for (int i = blockIdx.x * 8 + slot; i < BATCH; i += gridDim.x * 8) {
    float2 u = *(const float2*)&uacc[(size_t)i * D + 2 * sub];
    float2 b0 = *(const float2*)&bacc[(size_t)(2 * i) * D + 2 * sub];
    float2 b1 = *(const float2*)&bacc[(size_t)(2 * i + 1) * D + 2 * sub];
    float tt = (u.x * (b1.x - b0.x) + u.y * (b1.y - b0.y)) * (1.f / 16.f);
    for (int off = 16; off; off >>= 1) tt += __shfl_down(tt, off, 32);
    if (sub == 0) {
      float z = tt;
      acc += z > 0.f ? z + log1pf(expf(-z)) : log1pf(expf(z));
    }
  }
  if (sub == 0) bsum[slot] = acc;
  __syncthreads();
  if (t == 0) {
    float s = 0.f;
    for (int k = 0; k < 8; ++k) s += bsum[k];
    atomicAdd(&out[0], s * (1.f / (float)BATCH));
  }
}

extern "C" void kernel_launch(void* const* d_in, const int* in_sizes, int n_in,
                              void* d_out, int out_size, void* d_ws,
                              size_t ws_size, hipStream_t stream) {
  const float* emb_u = (const float*)d_in[0];
  const float* emb_b = (const float*)d_in[1];
  const float* filter_w = (const float*)d_in[2];
  const float* vals = (const float*)d_in[3];
  const int* rows = (const int*)d_in[4];
  const int* cols = (const int*)d_in[5];
  const int* u_idx = (const int*)d_in[6];
  const int* b_idx = (const int*)d_in[7];
  float* out = (float*)d_out;

  // workspace layout: bucket buffers (dead after CSR build) ALIASED with yH
  // only; uacc/bacc un-aliased (written during csr_concat's gather blocks).
  char* base = (char*)d_ws;
  u64* bufC = (u64*)base;                               // NWC*CAPC u64
  u64* bufR = bufC + (size_t)NWC * CAPC;                // NWR*CAPR u64
  unsigned* yH = (unsigned*)base;                       // N_IU*16 u32 (alias)
  char* after = base + ((size_t)NWC * CAPC + (size_t)NWR * CAPR) * 8;
  unsigned* xA = (unsigned*)after;                      // N_UB*16 u32
  unsigned* ec = xA + (size_t)N_UB * 16;                // NNZ
  unsigned* er = ec + NNZ;                              // NNZ
  int* ptrc = (int*)(er + NNZ);                         // N_IU+1
  int* ptrr = ptrc + (N_IU + 1);                        // N_UB+1
  int* gcurC = ptrr + (N_UB + 1);                       // NWC
  int* gcurR = gcurC + NWC;                             // NWR
  float* uacc = (float*)(gcurR + NWR);                  // BATCH*D
  float* bacc = uacc + (size_t)BATCH * D;               // 2*BATCH*D

  hipMemsetAsync(out, 0, 2 * sizeof(float), stream);
  hipMemsetAsync(gcurC, 0, NWIN * sizeof(int), stream);

  // bucket edges by node-window (both sides)
  bucket_kernel<<<NBLK_B, 1024, 0, stream>>>(rows, cols, vals, gcurC, gcurR,
                                             bufC, bufR);
  // fused: per-window counting sort + concat->fp8 + l2 + x0 gather
  csr_concat_kernel<<<NWIN + CONCAT_BLKS + GBLK, 1024, 0, stream>>>(
      bufC, bufR, gcurC, gcurR, ec, er, ptrc, ptrr, emb_u, emb_b, xA, out,
      u_idx, b_idx, uacc, bacc);

  // ---- 3 layers ----
  for (int l = 0; l < NLAYER; ++l) {
    // col pass; for l>0 fuse the gather-acc of xA (produced by spmm_row(l-1))
    int colgrid = NCOLB + (l > 0 ? GAB : 0);
    spmm_col_kernel<<<colgrid, 256, 0, stream>>>(
        ptrc, ec, xA, filter_w + (size_t)l * N_IU, yH, u_idx, b_idx, uacc,
        bacc);
    if (l < NLAYER - 1) {
      spmm_row_kernel<<<NROWB, 256, 0, stream>>>(ptrr, er, yH, xA);
    } else {
      spmm_gather_last_kernel<<<(3 * BATCH + 15) / 16, 256, 0, stream>>>(
          ptrr, er, yH, u_idx, b_idx, uacc, bacc);
    }
  }

  loss_kernel<<<256, 256, 0, stream>>>(uacc, bacc, out);
}

// Round 11
// 331.822 us; speedup vs baseline: 1.4563x; 1.0633x over previous
//
#include <hip/hip_runtime.h>
#include <math.h>

#define NU 100000
#define NB 50000
#define NI 100000
#define D 64
#define NLAYER 3
#define NNZ 2000000
#define BATCH 8192
#define LEAKY 0.2f
#define N_UB (NU + NB)   // 150000
#define N_IU (NI + NU)   // 200000

#define VSCALE 16383.f   // 14-bit fixed-point for vals in [0,1)

// ---- windowed CSR build params ----
#define WBITS 10
#define WSZ 1024                        // node window; records fit in LDS
#define NWC ((N_IU + WSZ - 1) / WSZ)    // 196
#define NWR ((N_UB + WSZ - 1) / WSZ)    // 147
#define NWIN (NWC + NWR)                // 343
#define CAPC 11264                      // mean 10240 + ~10 sigma
#define CAPR 15360                      // mean 13653 + ~14 sigma
#define LCAP 15360                      // LDS record capacity (123 KB)
#define EPB 8192                        // edges per bucket block
#define NBLK_B ((NNZ + EPB - 1) / EPB)  // 245
#define CONCAT_BLKS 512
#define GBLK 384                        // 384*64 = 24576 = 3*BATCH (1024-thr)
#define NCOLB ((N_IU + 15) / 16)        // col blocks (256-thr)
#define NROWB ((N_UB + 15) / 16)        // row blocks
#define GAB ((3 * BATCH) / 16)          // fused gather blocks (256-thr)

typedef unsigned long long u64;
typedef float v2f __attribute__((ext_vector_type(2)));

// ---- fp8 e4m3 x4 pack/unpack (hardware cvt; roundtrip-consistent) ----
__device__ __forceinline__ unsigned pack_fp8x4(float a, float b, float c,
                                               float d) {
  int lo = __builtin_amdgcn_cvt_pk_fp8_f32(a, b, 0, false);
  int pk = __builtin_amdgcn_cvt_pk_fp8_f32(c, d, lo, true);
  return (unsigned)pk;
}
__device__ __forceinline__ void unpack_fp8x4(unsigned w, float f[4]) {
  v2f lo = __builtin_amdgcn_cvt_pk_f32_fp8((int)w, false);
  v2f hi = __builtin_amdgcn_cvt_pk_f32_fp8((int)w, true);
  f[0] = lo[0];
  f[1] = lo[1];
  f[2] = hi[0];
  f[3] = hi[1];
}

// ---------------------------------------------------------------------------
// fused dispatch 1:
//   blocks [0, NBLK_B): bucket edges into 1024-node windows (both sides)
//     single shared histogram -> long contiguous runs (write-coalescing)
//   blocks [NBLK_B, +CONCAT_BLKS): concat emb -> x (fp8) + l2 reduction
//   blocks [.., +GBLK): x0 gather -> uacc/bacc (direct write)
// record: payload32 = q<<18 | partner ; rec = payload<<10 | node_local
// ---------------------------------------------------------------------------
__global__ __launch_bounds__(1024) void bucket_concat_kernel(
    const int* __restrict__ rows, const int* __restrict__ cols,
    const float* __restrict__ vals, int* __restrict__ gcurC,
    int* __restrict__ gcurR, u64* __restrict__ bufC, u64* __restrict__ bufR,
    const float* __restrict__ emb_u, const float* __restrict__ emb_b,
    unsigned* __restrict__ x, float* __restrict__ out,
    const int* __restrict__ u_idx, const int* __restrict__ b_idx,
    float* __restrict__ uacc, float* __restrict__ bacc) {
  __shared__ int cntw[NWIN];
  __shared__ int basew[NWIN];
  __shared__ float fsum[16];
  int blk = blockIdx.x;
  int t = threadIdx.x;

  if (blk >= NBLK_B + CONCAT_BLKS) {
    // ---------------- x0 gather path (write, no +=) ----------------
    int i = (blk - NBLK_B - CONCAT_BLKS) * 64 + (t >> 4);
    int g = t & 15;
    const float* srcrow;
    float* dst;
    if (i < BATCH) {
      srcrow = emb_u + (size_t)u_idx[i] * D;
      dst = uacc + (size_t)i * D;
    } else {
      int j = i - BATCH;
      srcrow = emb_b + (size_t)b_idx[j] * D;
      dst = bacc + (size_t)j * D;
    }
    *(float4*)&dst[4 * g] = *(const float4*)&srcrow[4 * g];
    return;
  }

  if (blk >= NBLK_B) {
    // ---------------- concat + l2 path (fp8 out) ----------------
    const int total4 = (N_UB * D) / 4;
    const int nu4 = (NU * D) / 4;
    float sq = 0.f;
    for (int i = (blk - NBLK_B) * 1024 + t; i < total4;
         i += CONCAT_BLKS * 1024) {
      float4 v = (i < nu4) ? ((const float4*)emb_u)[i]
                           : ((const float4*)emb_b)[i - nu4];
      sq += v.x * v.x + v.y * v.y + v.z * v.z + v.w * v.w;
      x[i] = pack_fp8x4(v.x, v.y, v.z, v.w);
    }
    for (int off = 32; off; off >>= 1) sq += __shfl_down(sq, off);
    if ((t & 63) == 0) fsum[t >> 6] = sq;
    __syncthreads();
    if (t == 0) {
      float s = 0.f;
      for (int k = 0; k < 16; ++k) s += fsum[k];
      atomicAdd(&out[1], s * (0.5f / (float)NU));
    }
    return;
  }

  // ---------------- bucket path ----------------
  if (t < NWIN) cntw[t] = 0;
  __syncthreads();
  int e0 = blk * EPB;
  int e1 = e0 + EPB;
  if (e1 > NNZ) e1 = NNZ;
  for (int e = e0 + t; e < e1; e += 1024) {
    int c = cols[e];
    int r = rows[e];
    atomicAdd(&cntw[c >> WBITS], 1);
    atomicAdd(&cntw[NWC + (r >> WBITS)], 1);
  }
  __syncthreads();
  if (t < NWC)
    basew[t] = atomicAdd(&gcurC[t], cntw[t]);
  else if (t < NWIN)
    basew[t] = atomicAdd(&gcurR[t - NWC], cntw[t]);
  __syncthreads();
  if (t < NWIN) cntw[t] = 0;  // reuse as local cursors
  __syncthreads();
  for (int e = e0 + t; e < e1; e += 1024) {
    int c = cols[e];
    int r = rows[e];
    unsigned q = __float2uint_rn(vals[e] * VSCALE);
    int wc = c >> WBITS;
    int wr = r >> WBITS;
    int oc = atomicAdd(&cntw[wc], 1);
    u64 recC = ((u64)((q << 18) | (unsigned)r) << WBITS) |
               (unsigned)(c & (WSZ - 1));
    bufC[(size_t)wc * CAPC + basew[wc] + oc] = recC;
    int orr = atomicAdd(&cntw[NWC + wr], 1);
    u64 recR = ((u64)((q << 18) | (unsigned)c) << WBITS) |
               (unsigned)(r & (WSZ - 1));
    bufR[(size_t)wr * CAPR + basew[NWC + wr] + orr] = recR;
  }
}

// ---------------------------------------------------------------------------
// dispatch 2: per-window counting sort ENTIRELY in LDS.
// Load window records once (123 KB LDS), histogram, scan, write ptr slice,
// scatter to ec/er. One block per window; 343 blocks.
// ---------------------------------------------------------------------------
__global__ __launch_bounds__(1024) void csr_sort_kernel(
    const u64* __restrict__ bufC, const u64* __restrict__ bufR,
    const int* __restrict__ gcurC, const int* __restrict__ gcurR,
    unsigned* __restrict__ ec, unsigned* __restrict__ er,
    int* __restrict__ ptrc, int* __restrict__ ptrr) {
  __shared__ u64 recs[LCAP];
  __shared__ int lcnt[WSZ];
  __shared__ int wsum[16];
  __shared__ int wbase_s;
  int blk = blockIdx.x;
  int t = threadIdx.x;

  bool cside = blk < NWC;
  int win = cside ? blk : blk - NWC;
  const u64* buf = cside ? bufC + (size_t)win * CAPC : bufR + (size_t)win * CAPR;
  const int* gsz = cside ? gcurC : gcurR;
  int nwin = cside ? NWC : NWR;
  int nnode = cside ? N_IU : N_UB;
  unsigned* eo = cside ? ec : er;
  int* ptr = cside ? ptrc : ptrr;
  int cnt = gsz[win];
  if (cnt > LCAP) cnt = LCAP;  // safety (P ~ 1e-15)
  // winbase = sum of gsz[0..win)
  if (t == 0) wbase_s = 0;
  lcnt[t] = 0;
  __syncthreads();
  if (t < win) atomicAdd(&wbase_s, gsz[t]);
  // load records once into LDS
  for (int i = t; i < cnt; i += 1024) recs[i] = buf[i];
  __syncthreads();
  int winbase = wbase_s;
  // histogram from LDS
  for (int i = t; i < cnt; i += 1024)
    atomicAdd(&lcnt[(int)(recs[i] & (WSZ - 1))], 1);
  __syncthreads();
  // exclusive scan of 1024 counters (1/thread): wave shfl + 16-way merge
  int a = lcnt[t];
  int lane = t & 63, wid = t >> 6;
  int v = a;
#pragma unroll
  for (int off = 1; off < 64; off <<= 1) {
    int n = __shfl_up(v, off);
    if (lane >= off) v += n;
  }
  if (lane == 63) wsum[wid] = v;
  __syncthreads();
  if (t == 0) {
    int run = 0;
    for (int k = 0; k < 16; ++k) {
      int tmp = wsum[k];
      wsum[k] = run;
      run += tmp;
    }
  }
  __syncthreads();
  int excl = v - a + wsum[wid];
  lcnt[t] = excl;
  // write global ptr slice (WSZ == blockDim: one element per thread)
  int g = win * WSZ + t;
  if (g < nnode) ptr[g] = winbase + excl;
  if (t == 0 && win == nwin - 1) ptr[nnode] = NNZ;
  __syncthreads();
  // scatter payloads from LDS (output region ~60-120 KB, L2-resident)
  for (int i = t; i < cnt; i += 1024) {
    u64 rec = recs[i];
    int pos = winbase + atomicAdd(&lcnt[(int)(rec & (WSZ - 1))], 1);
    eo[pos] = (unsigned)(rec >> WBITS);
  }
}

// ---------------------------------------------------------------------------
// pass 1 (CSR by col): y[c] = leaky(filt[c]) * sum val*x[src]
// fp8 rows: 16 lanes/row, 4 rows/wave; unroll 8 batched (8 gathers in flight).
// Extra blocks [NCOLB,NCOLB+GAB): gather-acc of x into uacc/bacc (layers 1,2).
// ---------------------------------------------------------------------------
__global__ __launch_bounds__(256) void spmm_col_kernel(
    const int* __restrict__ ptrc, const unsigned* __restrict__ ec,
    const unsigned* __restrict__ x, const float* __restrict__ filt,
    unsigned* __restrict__ y, const int* __restrict__ u_idx,
    const int* __restrict__ b_idx, float* __restrict__ uacc,
    float* __restrict__ bacc) {
  int blk = blockIdx.x;
  if (blk >= NCOLB) {
    // -------- fused gather-acc path --------
    int t = threadIdx.x;
    int i = (blk - NCOLB) * 16 + (t >> 4);
    int g = t & 15;
    int src;
    float* dst;
    if (i < BATCH) {
      src = u_idx[i];
      dst = &uacc[(size_t)i * D];
    } else {
      int j = i - BATCH;
      src = NU + b_idx[j];
      dst = &bacc[(size_t)j * D];
    }
    float f4[4];
    unpack_fp8x4(x[(size_t)src * 16 + g], f4);
    float4* dp = (float4*)&dst[4 * g];
    float4 d = *dp;
    d.x += f4[0];
    d.y += f4[1];
    d.z += f4[2];
    d.w += f4[3];
    *dp = d;
    return;
  }
  int wv = blk * 4 + (threadIdx.x >> 6);
  int lane = threadIdx.x & 63;
  int g = lane & 15;
  int c = wv * 4 + (lane >> 4);
  if (c >= N_IU) return;
  int e = ptrc[c], e2 = ptrc[c + 1];
  float a0 = 0.f, a1 = 0.f, a2 = 0.f, a3 = 0.f;
  for (; e + 8 <= e2; e += 8) {
    unsigned p0 = __builtin_nontemporal_load(&ec[e]);
    unsigned p1 = __builtin_nontemporal_load(&ec[e + 1]);
    unsigned p2 = __builtin_nontemporal_load(&ec[e + 2]);
    unsigned p3 = __builtin_nontemporal_load(&ec[e + 3]);
    unsigned p4 = __builtin_nontemporal_load(&ec[e + 4]);
    unsigned p5 = __builtin_nontemporal_load(&ec[e + 5]);
    unsigned p6 = __builtin_nontemporal_load(&ec[e + 6]);
    unsigned p7 = __builtin_nontemporal_load(&ec[e + 7]);
    unsigned w0 = x[(size_t)(p0 & 0x3FFFFu) * 16 + g];
    unsigned w1 = x[(size_t)(p1 & 0x3FFFFu) * 16 + g];
    unsigned w2 = x[(size_t)(p2 & 0x3FFFFu) * 16 + g];
    unsigned w3 = x[(size_t)(p3 & 0x3FFFFu) * 16 + g];
    unsigned w4 = x[(size_t)(p4 & 0x3FFFFu) * 16 + g];
    unsigned w5 = x[(size_t)(p5 & 0x3FFFFu) * 16 + g];
    unsigned w6 = x[(size_t)(p6 & 0x3FFFFu) * 16 + g];
    unsigned w7 = x[(size_t)(p7 & 0x3FFFFu) * 16 + g];
    float f0[4], f1[4], f2[4], f3[4], f4_[4], f5[4], f6[4], f7[4];
    unpack_fp8x4(w0, f0);
    unpack_fp8x4(w1, f1);
    unpack_fp8x4(w2, f2);
    unpack_fp8x4(w3, f3);
    unpack_fp8x4(w4, f4_);
    unpack_fp8x4(w5, f5);
    unpack_fp8x4(w6, f6);
    unpack_fp8x4(w7, f7);
    float v0 = (float)(p0 >> 18), v1 = (float)(p1 >> 18);
    float v2 = (float)(p2 >> 18), v3 = (float)(p3 >> 18);
    float v4 = (float)(p4 >> 18), v5 = (float)(p5 >> 18);
    float v6 = (float)(p6 >> 18), v7 = (float)(p7 >> 18);
    a0 += v0 * f0[0] + v1 * f1[0] + v2 * f2[0] + v3 * f3[0] + v4 * f4_[0] +
          v5 * f5[0] + v6 * f6[0] + v7 * f7[0];
    a1 += v0 * f0[1] + v1 * f1[1] + v2 * f2[1] + v3 * f3[1] + v4 * f4_[1] +
          v5 * f5[1] + v6 * f6[1] + v7 * f7[1];
    a2 += v0 * f0[2] + v1 * f1[2] + v2 * f2[2] + v3 * f3[2] + v4 * f4_[2] +
          v5 * f5[2] + v6 * f6[2] + v7 * f7[2];
    a3 += v0 * f0[3] + v1 * f1[3] + v2 * f2[3] + v3 * f3[3] + v4 * f4_[3] +
          v5 * f5[3] + v6 * f6[3] + v7 * f7[3];
  }
  for (; e + 4 <= e2; e += 4) {
    unsigned p0 = __builtin_nontemporal_load(&ec[e]);
    unsigned p1 = __builtin_nontemporal_load(&ec[e + 1]);
    unsigned p2 = __builtin_nontemporal_load(&ec[e + 2]);
    unsigned p3 = __builtin_nontemporal_load(&ec[e + 3]);
    unsigned w0 = x[(size_t)(p0 & 0x3FFFFu) * 16 + g];
    unsigned w1 = x[(size_t)(p1 & 0x3FFFFu) * 16 + g];
    unsigned w2 = x[(size_t)(p2 & 0x3FFFFu) * 16 + g];
    unsigned w3 = x[(size_t)(p3 & 0x3FFFFu) * 16 + g];
    float f0[4], f1[4], f2[4], f3[4];
    unpack_fp8x4(w0, f0);
    unpack_fp8x4(w1, f1);
    unpack_fp8x4(w2, f2);
    unpack_fp8x4(w3, f3);
    float v0 = (float)(p0 >> 18), v1 = (float)(p1 >> 18);
    float v2 = (float)(p2 >> 18), v3 = (float)(p3 >> 18);
    a0 += v0 * f0[0] + v1 * f1[0] + v2 * f2[0] + v3 * f3[0];
    a1 += v0 * f0[1] + v1 * f1[1] + v2 * f2[1] + v3 * f3[1];
    a2 += v0 * f0[2] + v1 * f1[2] + v2 * f2[2] + v3 * f3[2];
    a3 += v0 * f0[3] + v1 * f1[3] + v2 * f2[3] + v3 * f3[3];
  }
  for (; e < e2; ++e) {
    unsigned p = __builtin_nontemporal_load(&ec[e]);
    unsigned w = x[(size_t)(p & 0x3FFFFu) * 16 + g];
    float f4[4];
    unpack_fp8x4(w, f4);
    float v = (float)(p >> 18);
    a0 += v * f4[0];
    a1 += v * f4[1];
    a2 += v * f4[2];
    a3 += v * f4[3];
  }
  float fw = filt[c];
  float f = (fw > 0.f ? fw : LEAKY * fw) * (1.f / VSCALE);
  y[(size_t)c * 16 + g] = pack_fp8x4(a0 * f, a1 * f, a2 * f, a3 * f);
}

// ---------------------------------------------------------------------------
// pass 2 (CSR by row): x[r] = sum val*y[src]; unroll 8 batched.
// ---------------------------------------------------------------------------
__global__ __launch_bounds__(256) void spmm_row_kernel(
    const int* __restrict__ ptrr, const unsigned* __restrict__ er,
    const unsigned* __restrict__ y, unsigned* __restrict__ x) {
  int wv = blockIdx.x * 4 + (threadIdx.x >> 6);
  int lane = threadIdx.x & 63;
  int g = lane & 15;
  int r = wv * 4 + (lane >> 4);
  if (r >= N_UB) return;
  int e = ptrr[r], e2 = ptrr[r + 1];
  float a0 = 0.f, a1 = 0.f, a2 = 0.f, a3 = 0.f;
  for (; e + 8 <= e2; e += 8) {
    unsigned p0 = __builtin_nontemporal_load(&er[e]);
    unsigned p1 = __builtin_nontemporal_load(&er[e + 1]);
    unsigned p2 = __builtin_nontemporal_load(&er[e + 2]);
    unsigned p3 = __builtin_nontemporal_load(&er[e + 3]);
    unsigned p4 = __builtin_nontemporal_load(&er[e + 4]);
    unsigned p5 = __builtin_nontemporal_load(&er[e + 5]);
    unsigned p6 = __builtin_nontemporal_load(&er[e + 6]);
    unsigned p7 = __builtin_nontemporal_load(&er[e + 7]);
    unsigned w0 = y[(size_t)(p0 & 0x3FFFFu) * 16 + g];
    unsigned w1 = y[(size_t)(p1 & 0x3FFFFu) * 16 + g];
    unsigned w2 = y[(size_t)(p2 & 0x3FFFFu) * 16 + g];
    unsigned w3 = y[(size_t)(p3 & 0x3FFFFu) * 16 + g];
    unsigned w4 = y[(size_t)(p4 & 0x3FFFFu) * 16 + g];
    unsigned w5 = y[(size_t)(p5 & 0x3FFFFu) * 16 + g];
    unsigned w6 = y[(size_t)(p6 & 0x3FFFFu) * 16 + g];
    unsigned w7 = y[(size_t)(p7 & 0x3FFFFu) * 16 + g];
    float f0[4], f1[4], f2[4], f3[4], f4_[4], f5[4], f6[4], f7[4];
    unpack_fp8x4(w0, f0);
    unpack_fp8x4(w1, f1);
    unpack_fp8x4(w2, f2);
    unpack_fp8x4(w3, f3);
    unpack_fp8x4(w4, f4_);
    unpack_fp8x4(w5, f5);
    unpack_fp8x4(w6, f6);
    unpack_fp8x4(w7, f7);
    float v0 = (float)(p0 >> 18), v1 = (float)(p1 >> 18);
    float v2 = (float)(p2 >> 18), v3 = (float)(p3 >> 18);
    float v4 = (float)(p4 >> 18), v5 = (float)(p5 >> 18);
    float v6 = (float)(p6 >> 18), v7 = (float)(p7 >> 18);
    a0 += v0 * f0[0] + v1 * f1[0] + v2 * f2[0] + v3 * f3[0] + v4 * f4_[0] +
          v5 * f5[0] + v6 * f6[0] + v7 * f7[0];
    a1 += v0 * f0[1] + v1 * f1[1] + v2 * f2[1] + v3 * f3[1] + v4 * f4_[1] +
          v5 * f5[1] + v6 * f6[1] + v7 * f7[1];
    a2 += v0 * f0[2] + v1 * f1[2] + v2 * f2[2] + v3 * f3[2] + v4 * f4_[2] +
          v5 * f5[2] + v6 * f6[2] + v7 * f7[2];
    a3 += v0 * f0[3] + v1 * f1[3] + v2 * f2[3] + v3 * f3[3] + v4 * f4_[3] +
          v5 * f5[3] + v6 * f6[3] + v7 * f7[3];
  }
  for (; e + 4 <= e2; e += 4) {
    unsigned p0 = __builtin_nontemporal_load(&er[e]);
    unsigned p1 = __builtin_nontemporal_load(&er[e + 1]);
    unsigned p2 = __builtin_nontemporal_load(&er[e + 2]);
    unsigned p3 = __builtin_nontemporal_load(&er[e + 3]);
    unsigned w0 = y[(size_t)(p0 & 0x3FFFFu) * 16 + g];
    unsigned w1 = y[(size_t)(p1 & 0x3FFFFu) * 16 + g];
    unsigned w2 = y[(size_t)(p2 & 0x3FFFFu) * 16 + g];
    unsigned w3 = y[(size_t)(p3 & 0x3FFFFu) * 16 + g];
    float f0[4], f1[4], f2[4], f3[4];
    unpack_fp8x4(w0, f0);
    unpack_fp8x4(w1, f1);
    unpack_fp8x4(w2, f2);
    unpack_fp8x4(w3, f3);
    float v0 = (float)(p0 >> 18), v1 = (float)(p1 >> 18);
    float v2 = (float)(p2 >> 18), v3 = (float)(p3 >> 18);
    a0 += v0 * f0[0] + v1 * f1[0] + v2 * f2[0] + v3 * f3[0];
    a1 += v0 * f0[1] + v1 * f1[1] + v2 * f2[1] + v3 * f3[1];
    a2 += v0 * f0[2] + v1 * f1[2] + v2 * f2[2] + v3 * f3[2];
    a3 += v0 * f0[3] + v1 * f1[3] + v2 * f2[3] + v3 * f3[3];
  }
  for (; e < e2; ++e) {
    unsigned p = __builtin_nontemporal_load(&er[e]);
    unsigned w = y[(size_t)(p & 0x3FFFFu) * 16 + g];
    float f4[4];
    unpack_fp8x4(w, f4);
    float v = (float)(p >> 18);
    a0 += v * f4[0];
    a1 += v * f4[1];
    a2 += v * f4[2];
    a3 += v * f4[3];
  }
  const float s = 1.f / VSCALE;
  x[(size_t)r * 16 + g] = pack_fp8x4(a0 * s, a1 * s, a2 * s, a3 * s);
}

// ---------------------------------------------------------------------------
// last layer pass 2 ONLY at gathered rows, accumulated into uacc/bacc (fp32)
// ---------------------------------------------------------------------------
__global__ __launch_bounds__(256) void spmm_gather_last_kernel(
    const int* __restrict__ ptrr, const unsigned* __restrict__ er,
    const unsigned* __restrict__ y, const int* __restrict__ u_idx,
    const int* __restrict__ b_idx, float* __restrict__ uacc,
    float* __restrict__ bacc) {
  int wv = blockIdx.x * 4 + (threadIdx.x >> 6);
  int lane = threadIdx.x & 63;
  int g = lane & 15;
  int i = wv * 4 + (lane >> 4);
  if (i >= 3 * BATCH) return;
  int row;
  float* dst;
  if (i < BATCH) {
    row = u_idx[i];
    dst = &uacc[(size_t)i * D];
  } else {
    int j = i - BATCH;
    row = NU + b_idx[j];
    dst = &bacc[(size_t)j * D];
  }
  int e = ptrr[row], e2 = ptrr[row + 1];
  float a0 = 0.f, a1 = 0.f, a2 = 0.f, a3 = 0.f;
  for (; e < e2; ++e) {
    unsigned p = er[e];
    unsigned w = y[(size_t)(p & 0x3FFFFu) * 16 + g];
    float f4[4];
    unpack_fp8x4(w, f4);
    float v = (float)(p >> 18);
    a0 += v * f4[0];
    a1 += v * f4[1];
    a2 += v * f4[2];
    a3 += v * f4[3];
  }
  const float s = 1.f / VSCALE;
  float4* dp = (float4*)&dst[4 * g];
  float4 d = *dp;
  d.x += a0 * s;
  d.y += a1 * s;
  d.z += a2 * s;
  d.w += a3 * s;
  *dp = d;
}

// ---------------------------------------------------------------------------
// loss: z = dot(u, b1-b0)/16; loss = mean softplus(z).
// grid-stride; register-accumulated; ONE atomic per block (256 total).
// ---------------------------------------------------------------------------
__global__ __launch_bounds__(256) void loss_kernel(
    const float* __restrict__ uacc, const float* __restrict__ bacc,
    float* __restrict__ out) {
  __shared__ float bsum[8];
  int t = threadIdx.x;
  int slot = t >> 5;  // 8 half-waves per block
  int sub = t & 31;
  float acc = 0.f;
  for (int i = blockIdx.x * 8 + slot; i < BATCH; i += gridDim.x * 8) {
    float2 u = *(const float2*)&uacc[(size_t)i * D + 2 * sub];
    float2 b0 = *(const float2*)&bacc[(size_t)(2 * i) * D + 2 * sub];
    float2 b1 = *(const float2*)&bacc[(size_t)(2 * i + 1) * D + 2 * sub];
    float tt = (u.x * (b1.x - b0.x) + u.y * (b1.y - b0.y)) * (1.f / 16.f);
    for (int off = 16; off; off >>= 1) tt += __shfl_down(tt, off, 32);
    if (sub == 0) {
      float z = tt;
      acc += z > 0.f ? z + log1pf(expf(-z)) : log1pf(expf(z));
    }
  }
  if (sub == 0) bsum[slot] = acc;
  __syncthreads();
  if (t == 0) {
    float s = 0.f;
    for (int k = 0; k < 8; ++k) s += bsum[k];
    atomicAdd(&out[0], s * (1.f / (float)BATCH));
  }
}

extern "C" void kernel_launch(void* const* d_in, const int* in_sizes, int n_in,
                              void* d_out, int out_size, void* d_ws,
                              size_t ws_size, hipStream_t stream) {
  const float* emb_u = (const float*)d_in[0];
  const float* emb_b = (const float*)d_in[1];
  const float* filter_w = (const float*)d_in[2];
  const float* vals = (const float*)d_in[3];
  const int* rows = (const int*)d_in[4];
  const int* cols = (const int*)d_in[5];
  const int* u_idx = (const int*)d_in[6];
  const int* b_idx = (const int*)d_in[7];
  float* out = (float*)d_out;

  // workspace layout: bucket buffers (dead after CSR build) ALIASED with yH.
  char* base = (char*)d_ws;
  u64* bufC = (u64*)base;                               // NWC*CAPC u64
  u64* bufR = bufC + (size_t)NWC * CAPC;                // NWR*CAPR u64
  unsigned* yH = (unsigned*)base;                       // N_IU*16 u32 (alias)
  char* after = base + ((size_t)NWC * CAPC + (size_t)NWR * CAPR) * 8;
  unsigned* xA = (unsigned*)after;                      // N_UB*16 u32
  unsigned* ec = xA + (size_t)N_UB * 16;                // NNZ
  unsigned* er = ec + NNZ;                              // NNZ
  int* ptrc = (int*)(er + NNZ);                         // N_IU+1
  int* ptrr = ptrc + (N_IU + 1);                        // N_UB+1
  int* gcurC = ptrr + (N_UB + 1);                       // NWC
  int* gcurR = gcurC + NWC;                             // NWR
  float* uacc = (float*)(gcurR + NWR);                  // BATCH*D
  float* bacc = uacc + (size_t)BATCH * D;               // 2*BATCH*D

  hipMemsetAsync(out, 0, 2 * sizeof(float), stream);
  hipMemsetAsync(gcurC, 0, NWIN * sizeof(int), stream);

  // fused: bucket edges + concat->fp8 + l2 + x0 gather
  bucket_concat_kernel<<<NBLK_B + CONCAT_BLKS + GBLK, 1024, 0, stream>>>(
      rows, cols, vals, gcurC, gcurR, bufC, bufR, emb_u, emb_b, xA, out, u_idx,
      b_idx, uacc, bacc);
  // per-window LDS counting sort -> ptr + ec/er
  csr_sort_kernel<<<NWIN, 1024, 0, stream>>>(bufC, bufR, gcurC, gcurR, ec, er,
                                             ptrc, ptrr);

  // ---- 3 layers ----
  for (int l = 0; l < NLAYER; ++l) {
    // col pass; for l>0 fuse the gather-acc of xA (produced by spmm_row(l-1))
    int colgrid = NCOLB + (l > 0 ? GAB : 0);
    spmm_col_kernel<<<colgrid, 256, 0, stream>>>(
        ptrc, ec, xA, filter_w + (size_t)l * N_IU, yH, u_idx, b_idx, uacc,
        bacc);
    if (l < NLAYER - 1) {
      spmm_row_kernel<<<NROWB, 256, 0, stream>>>(ptrr, er, yH, xA);
    } else {
      spmm_gather_last_kernel<<<(3 * BATCH + 15) / 16, 256, 0, stream>>>(
          ptrr, er, yH, u_idx, b_idx, uacc, bacc);
    }
  }

  loss_kernel<<<256, 256, 0, stream>>>(uacc, bacc, out);
}